// Round 5
// baseline (133.564 us; speedup 1.0000x reference)
//
#include <hip/hip_runtime.h>
#include <math.h>

#define NPLANES 24   // B*C = 8*3
#define FINF 3.402823466e38f

__host__ __device__ __forceinline__ int d_off(int li) {
    // cumulative float offset of d-level li inside dBase (sizes 256^2..4^2 x24)
    return 2097152 - (2097152 >> (2 * li));
}

__device__ __forceinline__ int refl(int v, int S) {
    if (v < 0) v = -v;
    if (v >= S) v = 2 * S - 2 - v;
    return v;
}

// Block-wide reductions over 256 threads; all threads must call.
__device__ __forceinline__ float bredMin(float v, float* red, int tid) {
    red[tid] = v; __syncthreads();
    for (int s = 128; s > 0; s >>= 1) {
        if (tid < s) red[tid] = fminf(red[tid], red[tid + s]);
        __syncthreads();
    }
    float r = red[0]; __syncthreads(); return r;
}
__device__ __forceinline__ float bredMax(float v, float* red, int tid) {
    red[tid] = v; __syncthreads();
    for (int s = 128; s > 0; s >>= 1) {
        if (tid < s) red[tid] = fmaxf(red[tid], red[tid + s]);
        __syncthreads();
    }
    float r = red[0]; __syncthreads(); return r;
}
__device__ __forceinline__ float bredSum(float v, float* red, int tid) {
    red[tid] = v; __syncthreads();
    for (int s = 128; s > 0; s >>= 1) {
        if (tid < s) red[tid] += red[tid + s];
        __syncthreads();
    }
    float r = red[0]; __syncthreads(); return r;
}

// 6-tap separable collapsed pyrdown stencil on an LDS plane of size SxS.
__device__ __forceinline__ float stencil6(const float* s, int S, int i, int j) {
    const float w[6] = {1.f, 5.f, 10.f, 10.f, 5.f, 1.f};
    int rx[6];
#pragma unroll
    for (int b = 0; b < 6; ++b) rx[b] = refl(2 * j - 2 + b, S);
    float acc = 0.f;
#pragma unroll
    for (int a = 0; a < 6; ++a) {
        int ry = refl(2 * i - 2 + a, S);
        const float* rp = s + ry * S;
        float r = 0.f;
#pragma unroll
        for (int b = 0; b < 6; ++b) r += w[b] * rp[rx[b]];
        acc += w[a] * r;
    }
    return acc * (1.f / 1024.f);
}

// Fused pyrdown L1+L2: x (512^2) -> pyr2 tile (16x32), d0 region (32x64), li=0
// tile min/max. pyr1 lives only in LDS (never touches HBM).
// Grid: 24 planes x 32 tiles (8x4 of 16x32) = 768 blocks.
__global__ __launch_bounds__(256) void fused_l12(const float* __restrict__ x,
                                                 float* __restrict__ pyr2,
                                                 float* __restrict__ d0,
                                                 float* __restrict__ tileMin,
                                                 float* __restrict__ tileMax) {
    __shared__ float smem[18256];
    __shared__ float red0[256], red1[256];
    float* sX  = smem;            // 76 x 140
    float* sH1 = smem + 10640;    // 76 x 68
    float* sP1 = smem + 15808;    // 36 x 68 (pyr1 patch)
    float* sH2 = smem;            // 36 x 32  (aliases dead sX)
    float* sOut = smem + 1152;    // 16 x 32
    float* sD  = smem + 1664;     // 32 x 65

    const int tid = threadIdx.x;
    const int p = blockIdx.x >> 5;
    const int t = blockIdx.x & 31;
    const int ty = t >> 2, tx = t & 3;
    const int oy = ty * 16, ox = tx * 32;          // pyr2 coords (S=128)
    const int p1y0 = 2 * oy - 2, p1x0 = 2 * ox - 2; // pyr1 patch origin
    const int xy0 = 4 * oy - 6, xx0 = 4 * ox - 6;   // x patch origin
    const float* xp = x + (size_t)p * 512 * 512;

    for (int k = tid; k < 76 * 140; k += 256) {
        int r = k / 140, c = k - r * 140;
        sX[k] = xp[refl(xy0 + r, 512) * 512 + refl(xx0 + c, 512)];
    }
    __syncthreads();
    // horizontal 6-tap (x -> pyr1 cols)
    for (int k = tid; k < 76 * 68; k += 256) {
        int r = k / 68, c1 = k - r * 68;
        const float* rp = sX + r * 140 + 2 * c1;
        sH1[k] = rp[0] + 5.f * rp[1] + 10.f * rp[2] + 10.f * rp[3] + 5.f * rp[4] + rp[5];
    }
    __syncthreads();
    // vertical 6-tap -> pyr1 patch
    for (int k = tid; k < 36 * 68; k += 256) {
        int r1 = k / 68, c1 = k - r1 * 68;
        const float* cp = sH1 + 2 * r1 * 68 + c1;
        sP1[k] = (cp[0] + 5.f * cp[68] + 10.f * cp[2 * 68] + 10.f * cp[3 * 68] +
                  5.f * cp[4 * 68] + cp[5 * 68]) * (1.f / 1024.f);
    }
    __syncthreads();
    // horizontal 6-tap (pyr1 -> pyr2 cols), reflect at S=256 on global pyr1 index
    for (int k = tid; k < 36 * 32; k += 256) {
        int r1 = k >> 5, c2 = k & 31;
        int b0 = 2 * (ox + c2) - 2;
        const float* rp = sP1 + r1 * 68;
        float s = rp[refl(b0, 256) - p1x0] + 5.f * rp[refl(b0 + 1, 256) - p1x0] +
                  10.f * rp[refl(b0 + 2, 256) - p1x0] + 10.f * rp[refl(b0 + 3, 256) - p1x0] +
                  5.f * rp[refl(b0 + 4, 256) - p1x0] + rp[refl(b0 + 5, 256) - p1x0];
        sH2[k] = s;
    }
    __syncthreads();
    // vertical 6-tap -> pyr2 out
    float* o2 = pyr2 + (size_t)p * 128 * 128;
    for (int k = tid; k < 16 * 32; k += 256) {
        int i = k >> 5, c2 = k & 31;
        int b0 = 2 * (oy + i) - 2;
        float s = sH2[(refl(b0, 256) - p1y0) * 32 + c2] +
                  5.f * sH2[(refl(b0 + 1, 256) - p1y0) * 32 + c2] +
                  10.f * sH2[(refl(b0 + 2, 256) - p1y0) * 32 + c2] +
                  10.f * sH2[(refl(b0 + 3, 256) - p1y0) * 32 + c2] +
                  5.f * sH2[(refl(b0 + 4, 256) - p1y0) * 32 + c2] +
                  sH2[(refl(b0 + 5, 256) - p1y0) * 32 + c2];
        float v = s * (1.f / 1024.f);
        sOut[k] = v;
        o2[(size_t)(oy + i) * 128 + ox + c2] = v;
    }
    __syncthreads();
    // d0 = |pyr1 - up(pyr2)| over pyr1 rows 2oy..2oy+31, cols 2ox..2ox+63
    float* dp = d0 + (size_t)p * 256 * 256;
    for (int k = tid; k < 32 * 64; k += 256) {
        int yy = k >> 6, xx = k & 63;
        float dv = fabsf(sP1[(yy + 2) * 68 + xx + 2] - sOut[(yy >> 1) * 32 + (xx >> 1)]);
        sD[yy * 65 + xx] = dv;
        dp[(size_t)(2 * oy + yy) * 256 + 2 * ox + xx] = dv;
    }
    __syncthreads();
    // li=0 tile stats: 8 tiles (2x4) of 16x16; 32 threads/tile
    {
        int s8 = tid >> 5, l = tid & 31;
        int tr = s8 >> 2, tc = s8 & 3;
        int rr = l >> 1, ch = (l & 1) * 8;
        const float* rowp = sD + (tr * 16 + rr) * 65 + tc * 16 + ch;
        float mn = FINF, mx = -FINF;
#pragma unroll
        for (int c = 0; c < 8; ++c) {
            float v = rowp[c];
            mn = fminf(mn, v); mx = fmaxf(mx, v);
        }
        red0[tid] = mn; red1[tid] = mx;
        __syncthreads();
        for (int st = 16; st > 0; st >>= 1) {
            if (l < st) {
                red0[tid] = fminf(red0[tid], red0[tid + st]);
                red1[tid] = fmaxf(red1[tid], red1[tid + st]);
            }
            __syncthreads();
        }
        if (l == 0) {
            int gidx = p * 256 + (2 * ty + tr) * 16 + (4 * tx + tc);
            tileMin[gidx] = red0[tid];
            tileMax[gidx] = red1[tid];
        }
    }
}

// One block per plane: pyr2 -> pyr3 (separable, LDS), d1 + li=1 full stats,
// li=0 reduce from tile stats, then pyr4..pyr8 chain + d2..d6 + li=2..6 stats.
__global__ __launch_bounds__(256) void plane_monolith(const float* __restrict__ pyr2,
                                                      float* __restrict__ dBase,
                                                      const float* __restrict__ tileMin,
                                                      const float* __restrict__ tileMax,
                                                      float* __restrict__ A,
                                                      float* __restrict__ B) {
    __shared__ float smem[28672];
    __shared__ float red[256];
    __shared__ float tMn[64], tMx[64], tmaxLds[16];
    float* sP2 = smem;           // 128x128 (becomes d1 in place)
    float* sH  = smem + 16384;   // 128x64, later chain buffers
    float* sP3 = smem + 24576;   // 64x64
    float* sd2 = sH;             // 4096
    float* sp4 = sH + 4096;      // 1024
    float* sd3 = sH + 5120;      // 1024
    float* sp5 = sH + 6144;      // 256
    float* sd4 = sH + 6400;      // 256
    float* sp6 = sH + 6656;      // 64
    float* sd5 = sH + 6720;      // 64
    float* sp7 = sH + 6784;      // 16
    float* sd6 = sH + 6800;      // 16
    const int tid = threadIdx.x;
    const int p = blockIdx.x;

    const float4* gp = (const float4*)(pyr2 + (size_t)p * 16384);
    float4* sv = (float4*)sP2;
    for (int k = tid; k < 4096; k += 256) sv[k] = gp[k];
    __syncthreads();
    // h-pass (128 rows x 64 cols)
    for (int k = tid; k < 8192; k += 256) {
        int r = k >> 6, c = k & 63;
        int b0 = 2 * c - 2;
        const float* rp = sP2 + r * 128;
        sH[k] = rp[refl(b0, 128)] + 5.f * rp[refl(b0 + 1, 128)] + 10.f * rp[refl(b0 + 2, 128)] +
                10.f * rp[refl(b0 + 3, 128)] + 5.f * rp[refl(b0 + 4, 128)] + rp[refl(b0 + 5, 128)];
    }
    __syncthreads();
    // v-pass -> sP3 (64x64)
    for (int k = tid; k < 4096; k += 256) {
        int r3 = k >> 6, c = k & 63;
        int b0 = 2 * r3 - 2;
        float s = sH[refl(b0, 128) * 64 + c] + 5.f * sH[refl(b0 + 1, 128) * 64 + c] +
                  10.f * sH[refl(b0 + 2, 128) * 64 + c] + 10.f * sH[refl(b0 + 3, 128) * 64 + c] +
                  5.f * sH[refl(b0 + 4, 128) * 64 + c] + sH[refl(b0 + 5, 128) * 64 + c];
        sP3[k] = s * (1.f / 1024.f);
    }
    __syncthreads();
    // d1 in place over sP2 + global write
    float* d1g = dBase + d_off(1) + (size_t)p * 16384;
    for (int k = tid; k < 16384; k += 256) {
        int y = k >> 7, xc = k & 127;
        float dv = fabsf(sP2[k] - sP3[(y >> 1) * 64 + (xc >> 1)]);
        sP2[k] = dv;
        d1g[k] = dv;
    }
    __syncthreads();
    // li=1 stats: 64 tiles of 16x16, 4 threads/tile (4-col strips)
    {
        int s = tid >> 2, q = tid & 3;
        int tr = s >> 3, tc = s & 7;
        float mn = FINF, mx = -FINF;
        for (int r = 0; r < 16; ++r) {
            const float* pp = sP2 + (tr * 16 + r) * 128 + tc * 16 + q * 4;
#pragma unroll
            for (int j = 0; j < 4; ++j) {
                float v = pp[j];
                mn = fminf(mn, v); mx = fmaxf(mx, v);
            }
        }
        __shared__ float r0[256], r1[256];
        r0[tid] = mn; r1[tid] = mx;
        __syncthreads();
        if (q < 2) { r0[tid] = fminf(r0[tid], r0[tid + 2]); r1[tid] = fmaxf(r1[tid], r1[tid + 2]); }
        __syncthreads();
        if (q == 0) { tMn[s] = fminf(r0[tid], r0[tid + 1]); tMx[s] = fmaxf(r1[tid], r1[tid + 1]); }
        __syncthreads();
        float a = (tid < 64) ? tMn[tid] : FINF;
        float b = (tid < 64) ? tMx[tid] : -FINF;
        float mnp = bredMin(a, red, tid);
        float mxp = bredMax(b, red, tid);
        float su = (tid < 64 && (tid >> 3) < 7 && (tid & 7) < 7) ? tMx[tid] : 0.f;
        float sum = bredSum(su, red, tid);
        if (tid == 0) {
            float inv = 1.f / (mxp - mnp);
            float lm = (sum * (1.f / 49.f) - mnp) * inv;
            float g = (1.f - lm) * (1.f - lm);
            A[1 * NPLANES + p] = g * inv;
            B[1 * NPLANES + p] = -mnp * g * inv;
        }
    }
    // li=0 reduce from kernel-1 tile stats (256 tiles, interior 15x15)
    {
        float tmn = tileMin[p * 256 + tid];
        float tmx = tileMax[p * 256 + tid];
        float mnp = bredMin(tmn, red, tid);
        float mxp = bredMax(tmx, red, tid);
        float su = ((tid >> 4) < 15 && (tid & 15) < 15) ? tmx : 0.f;
        float sum = bredSum(su, red, tid);
        if (tid == 0) {
            float inv = 1.f / (mxp - mnp);
            float lm = (sum * (1.f / 225.f) - mnp) * inv;
            float g = (1.f - lm) * (1.f - lm);
            A[0 * NPLANES + p] = g * inv;
            B[0 * NPLANES + p] = -mnp * g * inv;
        }
    }
    __syncthreads();

    // pyr4 (32x32) + d2 (64x64)
    float* d2g = dBase + d_off(2) + (size_t)p * 4096;
    for (int k = tid; k < 1024; k += 256) {
        int i = k >> 5, j = k & 31;
        float v = stencil6(sP3, 64, i, j);
        sp4[k] = v;
#pragma unroll
        for (int di = 0; di < 2; ++di)
#pragma unroll
            for (int dj = 0; dj < 2; ++dj) {
                int y = 2 * i + di, xx = 2 * j + dj;
                float dv = fabsf(sP3[y * 64 + xx] - v);
                sd2[y * 64 + xx] = dv;
                d2g[y * 64 + xx] = dv;
            }
    }
    __syncthreads();
    // pyr5 (16x16) + d3 (32x32)
    {
        int i = tid >> 4, j = tid & 15;
        float v = stencil6(sp4, 32, i, j);
        sp5[tid] = v;
        float* d3g = dBase + d_off(3) + (size_t)p * 1024;
#pragma unroll
        for (int di = 0; di < 2; ++di)
#pragma unroll
            for (int dj = 0; dj < 2; ++dj) {
                int y = 2 * i + di, xx = 2 * j + dj;
                float dv = fabsf(sp4[y * 32 + xx] - v);
                sd3[y * 32 + xx] = dv;
                d3g[y * 32 + xx] = dv;
            }
    }
    __syncthreads();
    // pyr6 (8x8) + d4 (16x16)
    if (tid < 64) {
        int i = tid >> 3, j = tid & 7;
        float v = stencil6(sp5, 16, i, j);
        sp6[tid] = v;
        float* d4g = dBase + d_off(4) + (size_t)p * 256;
#pragma unroll
        for (int di = 0; di < 2; ++di)
#pragma unroll
            for (int dj = 0; dj < 2; ++dj) {
                int y = 2 * i + di, xx = 2 * j + dj;
                float dv = fabsf(sp5[y * 16 + xx] - v);
                sd4[y * 16 + xx] = dv;
                d4g[y * 16 + xx] = dv;
            }
    }
    __syncthreads();
    // pyr7 (4x4) + d5 (8x8)
    if (tid < 16) {
        int i = tid >> 2, j = tid & 3;
        float v = stencil6(sp6, 8, i, j);
        sp7[tid] = v;
        float* d5g = dBase + d_off(5) + (size_t)p * 64;
#pragma unroll
        for (int di = 0; di < 2; ++di)
#pragma unroll
            for (int dj = 0; dj < 2; ++dj) {
                int y = 2 * i + di, xx = 2 * j + dj;
                float dv = fabsf(sp6[y * 8 + xx] - v);
                sd5[y * 8 + xx] = dv;
                d5g[y * 8 + xx] = dv;
            }
    }
    __syncthreads();
    // pyr8 (2x2) + d6 (4x4)
    if (tid < 4) {
        int i = tid >> 1, j = tid & 1;
        float v = stencil6(sp7, 4, i, j);
        float* d6g = dBase + d_off(6) + (size_t)p * 16;
#pragma unroll
        for (int di = 0; di < 2; ++di)
#pragma unroll
            for (int dj = 0; dj < 2; ++dj) {
                int y = 2 * i + di, xx = 2 * j + dj;
                float dv = fabsf(sp7[y * 4 + xx] - v);
                sd6[y * 4 + xx] = dv;
                d6g[y * 4 + xx] = dv;
            }
    }
    __syncthreads();

    // ---- stats li=2 (S=64, interior 3x3 tiles) ----
    {
        float mn = FINF, mx = -FINF;
        for (int k = tid; k < 4096; k += 256) {
            float v = sd2[k];
            mn = fminf(mn, v); mx = fmaxf(mx, v);
        }
        mn = bredMin(mn, red, tid);
        mx = bredMax(mx, red, tid);
        {
            int t = tid >> 4, r = tid & 15;
            int ty = t >> 2, tx = t & 3;
            const float* rowp = sd2 + (ty * 16 + r) * 64 + tx * 16;
            float sm = -FINF;
#pragma unroll
            for (int c = 0; c < 16; ++c) sm = fmaxf(sm, rowp[c]);
            red[tid] = sm;
        }
        __syncthreads();
        if (tid < 16) {
            float tm = -FINF;
            for (int r = 0; r < 16; ++r) tm = fmaxf(tm, red[tid * 16 + r]);
            tmaxLds[tid] = tm;
        }
        __syncthreads();
        if (tid == 0) {
            float s = 0.f;
            for (int ty = 0; ty < 3; ++ty)
                for (int tx = 0; tx < 3; ++tx) s += tmaxLds[ty * 4 + tx];
            float inv = 1.f / (mx - mn);
            float lm = (s * (1.f / 9.f) - mn) * inv;
            float g = (1.f - lm) * (1.f - lm);
            A[2 * NPLANES + p] = g * inv;
            B[2 * NPLANES + p] = -mn * g * inv;
        }
        __syncthreads();
    }
    // ---- stats li=3 (S=32, single interior tile) ----
    {
        float mn = FINF, mx = -FINF;
        for (int k = tid; k < 1024; k += 256) {
            float v = sd3[k];
            mn = fminf(mn, v); mx = fmaxf(mx, v);
        }
        mn = bredMin(mn, red, tid);
        mx = bredMax(mx, red, tid);
        float e = sd3[(tid >> 4) * 32 + (tid & 15)];
        float tm = bredMax(e, red, tid);
        if (tid == 0) {
            float inv = 1.f / (mx - mn);
            float lm = (tm - mn) * inv;
            float g = (1.f - lm) * (1.f - lm);
            A[3 * NPLANES + p] = g * inv;
            B[3 * NPLANES + p] = -mn * g * inv;
        }
    }
    // ---- stats li=4,5,6 (lm=0) ----
    {
        float v = sd4[tid];
        float mn = bredMin(v, red, tid);
        float mx = bredMax(v, red, tid);
        if (tid == 0) {
            float inv = 1.f / (mx - mn);
            A[4 * NPLANES + p] = inv; B[4 * NPLANES + p] = -mn * inv;
        }
    }
    {
        float v = (tid < 64) ? sd5[tid] : FINF;
        float mn = bredMin(v, red, tid);
        v = (tid < 64) ? sd5[tid] : -FINF;
        float mx = bredMax(v, red, tid);
        if (tid == 0) {
            float inv = 1.f / (mx - mn);
            A[5 * NPLANES + p] = inv; B[5 * NPLANES + p] = -mn * inv;
        }
    }
    {
        float v = (tid < 16) ? sd6[tid] : FINF;
        float mn = bredMin(v, red, tid);
        v = (tid < 16) ? sd6[tid] : -FINF;
        float mx = bredMax(v, red, tid);
        if (tid == 0) {
            float inv = 1.f / (mx - mn);
            A[6 * NPLANES + p] = inv; B[6 * NPLANES + p] = -mn * inv;
        }
    }
}

// Tiled final gather: block = 64x64 output tile of one image b.
__global__ __launch_bounds__(256) void final_kernel(const float* __restrict__ dBase,
                                                    const float* __restrict__ A,
                                                    const float* __restrict__ Bc,
                                                    float* __restrict__ out) {
    __shared__ float patch[1650];
    __shared__ float sBtot;
    const int tid = threadIdx.x;
    const int b = blockIdx.x >> 6;
    const int tile = blockIdx.x & 63;
    const int yb = (tile >> 3) << 6;
    const int xb = (tile & 7) << 6;

    if (tid == 0) {
        float s = 0.f;
        for (int k = 0; k < 7; ++k)
            for (int c = 0; c < 3; ++c) s += Bc[k * NPLANES + b * 3 + c];
        sBtot = s;
    }

    const int dims[7] = {34, 18, 10, 6, 4, 3, 3};
    const int lofs[7] = {0, 1156, 1480, 1580, 1616, 1632, 1641};
    int baseY[7], baseX[7];
#pragma unroll
    for (int li = 0; li < 7; ++li) {
        const int S = 256 >> li;
        const float s = 1.f / (float)(2 << li);
        baseY[li] = (int)floorf((yb + 0.5f) * s - 0.5f);
        baseX[li] = (int)floorf((xb + 0.5f) * s - 0.5f);
        const int dim = dims[li];
        const int n = dim * dim;
        const float* d0p = dBase + d_off(li) + (size_t)(b * 3) * S * S;
        const float* d1p = d0p + S * S;
        const float* d2p = d1p + S * S;
        const float A0 = A[li * NPLANES + b * 3 + 0];
        const float A1 = A[li * NPLANES + b * 3 + 1];
        const float A2 = A[li * NPLANES + b * 3 + 2];
        for (int k = tid; k < n; k += 256) {
            int r = k / dim, c = k - r * dim;
            int sr = min(max(baseY[li] + r, 0), S - 1);
            int sc = min(max(baseX[li] + c, 0), S - 1);
            int si = sr * S + sc;
            patch[lofs[li] + k] = A0 * d0p[si] + A1 * d1p[si] + A2 * d2p[si];
        }
    }
    __syncthreads();

    const int ty = tid >> 4, tx = tid & 15;
    const int gy0 = yb + (ty << 2), gx0 = xb + (tx << 2);
    float acc[4][4];
#pragma unroll
    for (int i = 0; i < 4; ++i)
#pragma unroll
        for (int j = 0; j < 4; ++j) acc[i][j] = 0.f;

#pragma unroll
    for (int li = 0; li < 7; ++li) {
        const int dim = dims[li];
        const float* P = patch + lofs[li];
        const float s = 1.f / (float)(2 << li);
        int pr[4], pc[4];
        float wy[4], wx[4];
#pragma unroll
        for (int k = 0; k < 4; ++k) {
            float fy = (gy0 + k + 0.5f) * s - 0.5f;
            float fl = floorf(fy);
            wy[k] = fy - fl;
            pr[k] = (int)fl - baseY[li];
            float fx = (gx0 + k + 0.5f) * s - 0.5f;
            fl = floorf(fx);
            wx[k] = fx - fl;
            pc[k] = (int)fl - baseX[li];
        }
#pragma unroll
        for (int i = 0; i < 4; ++i) {
            const float* r0 = P + pr[i] * dim;
            const float* r1 = r0 + dim;
#pragma unroll
            for (int j = 0; j < 4; ++j) {
                float a0 = r0[pc[j]], a1 = r0[pc[j] + 1];
                float b0 = r1[pc[j]], b1 = r1[pc[j] + 1];
                float h0 = a0 + wx[j] * (a1 - a0);
                float h1 = b0 + wx[j] * (b1 - b0);
                acc[i][j] += h0 + wy[i] * (h1 - h0);
            }
        }
    }

    const float bt = sBtot;
    float* op = out + ((size_t)b * 512 + gy0) * 512 + gx0;
#pragma unroll
    for (int i = 0; i < 4; ++i) {
        float4 v;
        v.x = (acc[i][0] + bt) * (1.f / 3.f);
        v.y = (acc[i][1] + bt) * (1.f / 3.f);
        v.z = (acc[i][2] + bt) * (1.f / 3.f);
        v.w = (acc[i][3] + bt) * (1.f / 3.f);
        *(float4*)(op + (size_t)i * 512) = v;
    }
}

extern "C" void kernel_launch(void* const* d_in, const int* in_sizes, int n_in,
                              void* d_out, int out_size, void* d_ws, size_t ws_size,
                              hipStream_t stream) {
    (void)in_sizes; (void)n_in; (void)out_size; (void)ws_size;
    const float* x = (const float*)d_in[0];
    float* ws = (float*)d_ws;
    float* out = (float*)d_out;

    // Workspace layout (float offsets):
    float* pyr2 = ws;                  // 128^2*24 = 393216
    float* dBase = ws + 393216;        // d0..d6   = 2097024
    float* tileMin = ws + 2490240;     // 6144
    float* tileMax = ws + 2496384;     // 6144
    float* A = ws + 2502528;           // 168
    float* Bc = ws + 2502696;          // 168

    fused_l12<<<NPLANES * 32, 256, 0, stream>>>(x, pyr2, dBase + d_off(0), tileMin, tileMax);
    plane_monolith<<<NPLANES, 256, 0, stream>>>(pyr2, dBase, tileMin, tileMax, A, Bc);
    final_kernel<<<8 * 64, 256, 0, stream>>>(dBase, A, Bc, out);
}

// Round 6
// 119.310 us; speedup vs baseline: 1.1195x; 1.1195x over previous
//
#include <hip/hip_runtime.h>
#include <math.h>

#define NPLANES 24   // B*C = 8*3
#define FINF 3.402823466e38f

__host__ __device__ __forceinline__ int d_off(int li) {
    // cumulative float offset of d-level li inside dBase (sizes 256^2..4^2 x24)
    return 2097152 - (2097152 >> (2 * li));
}

__device__ __forceinline__ int refl(int v, int S) {
    if (v < 0) v = -v;
    if (v >= S) v = 2 * S - 2 - v;
    return v;
}

// ---- wave-64 reductions (no LDS, no sync) ----
__device__ __forceinline__ float wmin64(float v) {
#pragma unroll
    for (int o = 32; o > 0; o >>= 1) v = fminf(v, __shfl_down(v, o, 64));
    return v;
}
__device__ __forceinline__ float wmax64(float v) {
#pragma unroll
    for (int o = 32; o > 0; o >>= 1) v = fmaxf(v, __shfl_down(v, o, 64));
    return v;
}
__device__ __forceinline__ float wsum64(float v) {
#pragma unroll
    for (int o = 32; o > 0; o >>= 1) v += __shfl_down(v, o, 64);
    return v;
}
// ---- block-1024 reductions (16 waves); all 1024 threads must call ----
__device__ __forceinline__ float bmin1024(float v, float* cross, int tid) {
    v = wmin64(v);
    if ((tid & 63) == 0) cross[tid >> 6] = v;
    __syncthreads();
    if (tid < 16) {
        float t = cross[tid];
#pragma unroll
        for (int o = 8; o > 0; o >>= 1) t = fminf(t, __shfl_down(t, o, 16));
        if (tid == 0) cross[0] = t;
    }
    __syncthreads();
    float r = cross[0];
    __syncthreads();
    return r;
}
__device__ __forceinline__ float bmax1024(float v, float* cross, int tid) {
    v = wmax64(v);
    if ((tid & 63) == 0) cross[tid >> 6] = v;
    __syncthreads();
    if (tid < 16) {
        float t = cross[tid];
#pragma unroll
        for (int o = 8; o > 0; o >>= 1) t = fmaxf(t, __shfl_down(t, o, 16));
        if (tid == 0) cross[0] = t;
    }
    __syncthreads();
    float r = cross[0];
    __syncthreads();
    return r;
}
__device__ __forceinline__ float bsum1024(float v, float* cross, int tid) {
    v = wsum64(v);
    if ((tid & 63) == 0) cross[tid >> 6] = v;
    __syncthreads();
    if (tid < 16) {
        float t = cross[tid];
#pragma unroll
        for (int o = 8; o > 0; o >>= 1) t += __shfl_down(t, o, 16);
        if (tid == 0) cross[0] = t;
    }
    __syncthreads();
    float r = cross[0];
    __syncthreads();
    return r;
}

// 6-tap separable collapsed pyrdown stencil on an LDS plane of size SxS.
__device__ __forceinline__ float stencil6(const float* s, int S, int i, int j) {
    const float w[6] = {1.f, 5.f, 10.f, 10.f, 5.f, 1.f};
    int rx[6];
#pragma unroll
    for (int b = 0; b < 6; ++b) rx[b] = refl(2 * j - 2 + b, S);
    float acc = 0.f;
#pragma unroll
    for (int a = 0; a < 6; ++a) {
        int ry = refl(2 * i - 2 + a, S);
        const float* rp = s + ry * S;
        float r = 0.f;
#pragma unroll
        for (int b = 0; b < 6; ++b) r += w[b] * rp[rx[b]];
        acc += w[a] * r;
    }
    return acc * (1.f / 1024.f);
}

// Tiled separable pyrdown (R4-verified). Block = 32x32 output tile of one plane.
template <int IS, bool HAS_D, int LI>
__global__ __launch_bounds__(256) void pyrdown_tiled(const float* __restrict__ in,
                                                     float* __restrict__ out,
                                                     float* __restrict__ dout,
                                                     float* __restrict__ tileMin,
                                                     float* __restrict__ tileMax) {
    constexpr int SO = IS / 2;
    constexpr int TO = 32;            // output tile edge
    constexpr int TI = 2 * TO + 4;    // 68 staged input edge
    constexpr int TPA = SO / TO;      // output tiles per axis
    __shared__ float sIn[TI * TI];    // 4624
    __shared__ float sH[TI * TO];     // 2176
    __shared__ float sOut[TO * TO];   // 1024
    __shared__ float sD[HAS_D ? 64 * 65 : 1];
    __shared__ float rmn[HAS_D ? 256 : 1], rmx[HAS_D ? 256 : 1];

    const int tid = threadIdx.x;
    const int p = blockIdx.x / (TPA * TPA);
    const int t = blockIdx.x % (TPA * TPA);
    const int ty = t / TPA, tx = t % TPA;
    const int oy = ty * TO, ox = tx * TO;
    const int iy = 2 * oy - 2, ix = 2 * ox - 2;
    const float* ip = in + (size_t)p * IS * IS;

    for (int k = tid; k < TI * TI; k += 256) {
        int r = k / TI, c = k - r * TI;
        sIn[k] = ip[refl(iy + r, IS) * IS + refl(ix + c, IS)];
    }
    __syncthreads();

    for (int k = tid; k < TI * TO; k += 256) {
        int r = k / TO, j = k - r * TO;
        const float* rp = sIn + r * TI + 2 * j;
        sH[k] = rp[0] + 5.f * rp[1] + 10.f * rp[2] + 10.f * rp[3] + 5.f * rp[4] + rp[5];
    }
    __syncthreads();

    float* op = out + (size_t)p * SO * SO;
    for (int k = tid; k < TO * TO; k += 256) {
        int i = k / TO, j = k - i * TO;
        const float* cp = sH + (2 * i) * TO + j;
        float v = (cp[0] + 5.f * cp[TO] + 10.f * cp[2 * TO] + 10.f * cp[3 * TO] +
                   5.f * cp[4 * TO] + cp[5 * TO]) * (1.f / 1024.f);
        sOut[k] = v;
        op[(size_t)(oy + i) * SO + ox + j] = v;
    }

    if (HAS_D) {
        __syncthreads();
        float* dp = dout + (size_t)p * IS * IS;
        for (int k = tid; k < 4096; k += 256) {
            int yy = k >> 6, xx = k & 63;
            float dv = fabsf(sIn[(yy + 2) * TI + xx + 2] - sOut[(yy >> 1) * TO + (xx >> 1)]);
            sD[yy * 65 + xx] = dv;
            dp[(size_t)(2 * oy + yy) * IS + 2 * ox + xx] = dv;
        }
        __syncthreads();
        int s = tid >> 4, r = tid & 15;
        int tr = s >> 2, tc = s & 3;
        const float* rowp = sD + (tr * 16 + r) * 65 + tc * 16;
        float mn = FINF, mx = -FINF;
#pragma unroll
        for (int c = 0; c < 16; ++c) {
            float v = rowp[c];
            mn = fminf(mn, v); mx = fmaxf(mx, v);
        }
        rmn[tid] = mn; rmx[tid] = mx;
        __syncthreads();
        for (int st = 8; st > 0; st >>= 1) {
            if (r < st) {
                rmn[tid] = fminf(rmn[tid], rmn[tid + st]);
                rmx[tid] = fmaxf(rmx[tid], rmx[tid + st]);
            }
            __syncthreads();
        }
        if (r == 0) {
            constexpr int TA = IS / 16;
            constexpr int baseLi = (LI == 0) ? 0 : 6144;
            int gidx = baseLi + p * TA * TA + (ty * 4 + tr) * TA + (tx * 4 + tc);
            tileMin[gidx] = rmn[tid];
            tileMax[gidx] = rmx[tid];
        }
    }
}

// One block (1024 threads) per plane: pyr4..pyr8 + d2..d6 in LDS, stats for
// li=2..6, plus the li=0/li=1 tile-stat reductions (old reduce_kernel folded in).
__global__ __launch_bounds__(1024) void fused_small_kernel(const float* __restrict__ pyr3,
                                                           float* __restrict__ dBase,
                                                           const float* __restrict__ tileMin,
                                                           const float* __restrict__ tileMax,
                                                           float* __restrict__ A,
                                                           float* __restrict__ B) {
    __shared__ float sp3[4096], sd2[4096];
    __shared__ float sp4[1024], sd3[1024];
    __shared__ float sp5[256], sd4[256];
    __shared__ float sp6[64], sd5[64];
    __shared__ float sp7[16], sd6[16];
    __shared__ float cross[16];
    __shared__ float strip[256];
    __shared__ float tmaxLds[16];
    const int tid = threadIdx.x;
    const int p = blockIdx.x;

    ((float4*)sp3)[tid] = ((const float4*)(pyr3 + (size_t)p * 4096))[tid];
    __syncthreads();

    // pyr4 (32x32) + d2 (64x64): one output per thread
    {
        float* d2g = dBase + d_off(2) + (size_t)p * 4096;
        int i = tid >> 5, j = tid & 31;
        float v = stencil6(sp3, 64, i, j);
        sp4[tid] = v;
#pragma unroll
        for (int di = 0; di < 2; ++di)
#pragma unroll
            for (int dj = 0; dj < 2; ++dj) {
                int y = 2 * i + di, x = 2 * j + dj;
                float dv = fabsf(sp3[y * 64 + x] - v);
                sd2[y * 64 + x] = dv;
                d2g[y * 64 + x] = dv;
            }
    }
    __syncthreads();
    // pyr5 (16x16) + d3 (32x32)
    if (tid < 256) {
        int i = tid >> 4, j = tid & 15;
        float v = stencil6(sp4, 32, i, j);
        sp5[tid] = v;
        float* d3g = dBase + d_off(3) + (size_t)p * 1024;
#pragma unroll
        for (int di = 0; di < 2; ++di)
#pragma unroll
            for (int dj = 0; dj < 2; ++dj) {
                int y = 2 * i + di, x = 2 * j + dj;
                float dv = fabsf(sp4[y * 32 + x] - v);
                sd3[y * 32 + x] = dv;
                d3g[y * 32 + x] = dv;
            }
    }
    __syncthreads();
    // pyr6 (8x8) + d4 (16x16)
    if (tid < 64) {
        int i = tid >> 3, j = tid & 7;
        float v = stencil6(sp5, 16, i, j);
        sp6[tid] = v;
        float* d4g = dBase + d_off(4) + (size_t)p * 256;
#pragma unroll
        for (int di = 0; di < 2; ++di)
#pragma unroll
            for (int dj = 0; dj < 2; ++dj) {
                int y = 2 * i + di, x = 2 * j + dj;
                float dv = fabsf(sp5[y * 16 + x] - v);
                sd4[y * 16 + x] = dv;
                d4g[y * 16 + x] = dv;
            }
    }
    __syncthreads();
    // pyr7 (4x4) + d5 (8x8)
    if (tid < 16) {
        int i = tid >> 2, j = tid & 3;
        float v = stencil6(sp6, 8, i, j);
        sp7[tid] = v;
        float* d5g = dBase + d_off(5) + (size_t)p * 64;
#pragma unroll
        for (int di = 0; di < 2; ++di)
#pragma unroll
            for (int dj = 0; dj < 2; ++dj) {
                int y = 2 * i + di, x = 2 * j + dj;
                float dv = fabsf(sp6[y * 8 + x] - v);
                sd5[y * 8 + x] = dv;
                d5g[y * 8 + x] = dv;
            }
    }
    __syncthreads();
    // pyr8 (2x2) + d6 (4x4)
    if (tid < 4) {
        int i = tid >> 1, j = tid & 1;
        float v = stencil6(sp7, 4, i, j);
        float* d6g = dBase + d_off(6) + (size_t)p * 16;
#pragma unroll
        for (int di = 0; di < 2; ++di)
#pragma unroll
            for (int dj = 0; dj < 2; ++dj) {
                int y = 2 * i + di, x = 2 * j + dj;
                float dv = fabsf(sp7[y * 4 + x] - v);
                sd6[y * 4 + x] = dv;
                d6g[y * 4 + x] = dv;
            }
    }
    __syncthreads();

    // ---- stats li=2 (S=64, interior 3x3 of 4x4 tiles) ----
    {
        float4 q = ((const float4*)sd2)[tid];
        float mn = fminf(fminf(q.x, q.y), fminf(q.z, q.w));
        float mx = fmaxf(fmaxf(q.x, q.y), fmaxf(q.z, q.w));
        mn = bmin1024(mn, cross, tid);
        mx = bmax1024(mx, cross, tid);
        if (tid < 256) {
            int t = tid >> 4, r = tid & 15;
            int ty = t >> 2, tx = t & 3;
            const float* rowp = sd2 + (ty * 16 + r) * 64 + tx * 16;
            float sm = -FINF;
#pragma unroll
            for (int c = 0; c < 16; ++c) sm = fmaxf(sm, rowp[c]);
            strip[tid] = sm;
        }
        __syncthreads();
        if (tid < 16) {
            float tm = -FINF;
            for (int r = 0; r < 16; ++r) tm = fmaxf(tm, strip[tid * 16 + r]);
            tmaxLds[tid] = tm;
        }
        __syncthreads();
        if (tid == 0) {
            float s = 0.f;
            for (int ty = 0; ty < 3; ++ty)
                for (int tx = 0; tx < 3; ++tx) s += tmaxLds[ty * 4 + tx];
            float inv = 1.f / (mx - mn);
            float lm = (s * (1.f / 9.f) - mn) * inv;
            float g = (1.f - lm) * (1.f - lm);
            A[2 * NPLANES + p] = g * inv;
            B[2 * NPLANES + p] = -mn * g * inv;
        }
        __syncthreads();
    }
    // ---- stats li=3 (S=32, single interior 16x16 tile) ----
    {
        float v = sd3[tid];
        float mn = bmin1024(v, cross, tid);
        float mx = bmax1024(v, cross, tid);
        float e = (tid < 256) ? sd3[(tid >> 4) * 32 + (tid & 15)] : -FINF;
        float tm = bmax1024(e, cross, tid);
        if (tid == 0) {
            float inv = 1.f / (mx - mn);
            float lm = (tm - mn) * inv;
            float g = (1.f - lm) * (1.f - lm);
            A[3 * NPLANES + p] = g * inv;
            B[3 * NPLANES + p] = -mn * g * inv;
        }
    }
    // ---- stats li=4,5,6 (lm=0) ----
    {
        float v = (tid < 256) ? sd4[tid] : FINF;
        float mn = bmin1024(v, cross, tid);
        v = (tid < 256) ? sd4[tid] : -FINF;
        float mx = bmax1024(v, cross, tid);
        if (tid == 0) {
            float inv = 1.f / (mx - mn);
            A[4 * NPLANES + p] = inv; B[4 * NPLANES + p] = -mn * inv;
        }
    }
    {
        float v = (tid < 64) ? sd5[tid] : FINF;
        float mn = bmin1024(v, cross, tid);
        v = (tid < 64) ? sd5[tid] : -FINF;
        float mx = bmax1024(v, cross, tid);
        if (tid == 0) {
            float inv = 1.f / (mx - mn);
            A[5 * NPLANES + p] = inv; B[5 * NPLANES + p] = -mn * inv;
        }
    }
    {
        float v = (tid < 16) ? sd6[tid] : FINF;
        float mn = bmin1024(v, cross, tid);
        v = (tid < 16) ? sd6[tid] : -FINF;
        float mx = bmax1024(v, cross, tid);
        if (tid == 0) {
            float inv = 1.f / (mx - mn);
            A[6 * NPLANES + p] = inv; B[6 * NPLANES + p] = -mn * inv;
        }
    }
    // ---- li=0 reduce from tile stats (256 tiles, interior 15x15) ----
    {
        float tmn = (tid < 256) ? tileMin[p * 256 + tid] : FINF;
        float tmx = (tid < 256) ? tileMax[p * 256 + tid] : -FINF;
        float mn = bmin1024(tmn, cross, tid);
        float mx = bmax1024(tmx, cross, tid);
        float su = (tid < 256 && (tid >> 4) < 15 && (tid & 15) < 15) ? tmx : 0.f;
        float sum = bsum1024(su, cross, tid);
        if (tid == 0) {
            float inv = 1.f / (mx - mn);
            float lm = (sum * (1.f / 225.f) - mn) * inv;
            float g = (1.f - lm) * (1.f - lm);
            A[0 * NPLANES + p] = g * inv;
            B[0 * NPLANES + p] = -mn * g * inv;
        }
    }
    // ---- li=1 reduce from tile stats (64 tiles, interior 7x7) ----
    {
        float tmn = (tid < 64) ? tileMin[6144 + p * 64 + tid] : FINF;
        float tmx = (tid < 64) ? tileMax[6144 + p * 64 + tid] : -FINF;
        float mn = bmin1024(tmn, cross, tid);
        float mx = bmax1024(tmx, cross, tid);
        float su = (tid < 64 && (tid >> 3) < 7 && (tid & 7) < 7) ? tmx : 0.f;
        float sum = bsum1024(su, cross, tid);
        if (tid == 0) {
            float inv = 1.f / (mx - mn);
            float lm = (sum * (1.f / 49.f) - mn) * inv;
            float g = (1.f - lm) * (1.f - lm);
            A[1 * NPLANES + p] = g * inv;
            B[1 * NPLANES + p] = -mn * g * inv;
        }
    }
}

// Tiled final gather, register-patch bilerp: block = 64x64 output tile of image b.
// Per level each thread loads a 4x4 (level 0) / 3x3 (levels 1-6) register patch
// covering its whole 4x4 output sub-block, then selects rows/cols branchlessly.
// LDS reads drop 448 -> 70 per thread vs the per-pixel gather.
__global__ __launch_bounds__(256) void final_kernel(const float* __restrict__ dBase,
                                                    const float* __restrict__ A,
                                                    const float* __restrict__ Bc,
                                                    float* __restrict__ out) {
    __shared__ float patch[1700];   // 1650 used + pad for benign 3x3 overread
    __shared__ float sBtot;
    const int tid = threadIdx.x;
    const int b = blockIdx.x >> 6;
    const int tile = blockIdx.x & 63;
    const int yb = (tile >> 3) << 6;
    const int xb = (tile & 7) << 6;

    if (tid == 0) {
        float s = 0.f;
        for (int k = 0; k < 7; ++k)
            for (int c = 0; c < 3; ++c) s += Bc[k * NPLANES + b * 3 + c];
        sBtot = s;
    }

    const int dims[7] = {34, 18, 10, 6, 4, 3, 3};
    const int lofs[7] = {0, 1156, 1480, 1580, 1616, 1632, 1641};
    int baseY[7], baseX[7];
#pragma unroll
    for (int li = 0; li < 7; ++li) {
        const int S = 256 >> li;
        const float s = 1.f / (float)(2 << li);
        baseY[li] = (int)floorf((yb + 0.5f) * s - 0.5f);
        baseX[li] = (int)floorf((xb + 0.5f) * s - 0.5f);
        const int dim = dims[li];
        const int n = dim * dim;
        const float* d0p = dBase + d_off(li) + (size_t)(b * 3) * S * S;
        const float* d1p = d0p + S * S;
        const float* d2p = d1p + S * S;
        const float A0 = A[li * NPLANES + b * 3 + 0];
        const float A1 = A[li * NPLANES + b * 3 + 1];
        const float A2 = A[li * NPLANES + b * 3 + 2];
        for (int k = tid; k < n; k += 256) {
            int r = k / dim, c = k - r * dim;
            int sr = min(max(baseY[li] + r, 0), S - 1);
            int sc = min(max(baseX[li] + c, 0), S - 1);
            int si = sr * S + sc;
            patch[lofs[li] + k] = A0 * d0p[si] + A1 * d1p[si] + A2 * d2p[si];
        }
    }
    __syncthreads();

    const int ty = tid >> 4, tx = tid & 15;
    const int gy0 = yb + (ty << 2), gx0 = xb + (tx << 2);
    float acc[4][4];
#pragma unroll
    for (int i = 0; i < 4; ++i)
#pragma unroll
        for (int j = 0; j < 4; ++j) acc[i][j] = 0.f;

    // ---- level 0 (scale 1/2): 4x4 register patch ----
    {
        const int dim = 34;
        float wy[4], wx[4];
        int ry[4], cx[4];
#pragma unroll
        for (int k = 0; k < 4; ++k) {
            float fy = (gy0 + k + 0.5f) * 0.5f - 0.5f;
            float fl = floorf(fy);
            wy[k] = fy - fl; ry[k] = (int)fl - baseY[0];
            float fx = (gx0 + k + 0.5f) * 0.5f - 0.5f;
            fl = floorf(fx);
            wx[k] = fx - fl; cx[k] = (int)fl - baseX[0];
        }
        const int r0 = ry[0], c0 = cx[0];
        const float* pp = patch + r0 * dim + c0;
        float P[4][4];
#pragma unroll
        for (int r = 0; r < 4; ++r)
#pragma unroll
            for (int c = 0; c < 4; ++c) P[r][c] = pp[r * dim + c];
        float h[4][4];
#pragma unroll
        for (int j = 0; j < 4; ++j) {
            int dx = cx[j] - c0;
#pragma unroll
            for (int r = 0; r < 4; ++r) {
                float a = dx == 0 ? P[r][0] : (dx == 1 ? P[r][1] : P[r][2]);
                float bb = dx == 0 ? P[r][1] : (dx == 1 ? P[r][2] : P[r][3]);
                h[r][j] = a + wx[j] * (bb - a);
            }
        }
#pragma unroll
        for (int i = 0; i < 4; ++i) {
            int dy = ry[i] - r0;
#pragma unroll
            for (int j = 0; j < 4; ++j) {
                float h0 = dy == 0 ? h[0][j] : (dy == 1 ? h[1][j] : h[2][j]);
                float h1 = dy == 0 ? h[1][j] : (dy == 1 ? h[2][j] : h[3][j]);
                acc[i][j] += h0 + wy[i] * (h1 - h0);
            }
        }
    }
    // ---- levels 1..6 (scale <= 1/4): 3x3 register patch ----
#pragma unroll
    for (int li = 1; li < 7; ++li) {
        const int dim = dims[li];
        const float* P0 = patch + lofs[li];
        const float s = 1.f / (float)(2 << li);
        float wy[4], wx[4];
        int ry[4], cx[4];
#pragma unroll
        for (int k = 0; k < 4; ++k) {
            float fy = (gy0 + k + 0.5f) * s - 0.5f;
            float fl = floorf(fy);
            wy[k] = fy - fl; ry[k] = (int)fl - baseY[li];
            float fx = (gx0 + k + 0.5f) * s - 0.5f;
            fl = floorf(fx);
            wx[k] = fx - fl; cx[k] = (int)fl - baseX[li];
        }
        const int r0 = ry[0], c0 = cx[0];
        const float* pp = P0 + r0 * dim + c0;
        float P[3][3];
#pragma unroll
        for (int r = 0; r < 3; ++r)
#pragma unroll
            for (int c = 0; c < 3; ++c) P[r][c] = pp[r * dim + c];
        float h[3][4];
#pragma unroll
        for (int j = 0; j < 4; ++j) {
            int dx = cx[j] - c0;   // 0 or 1
#pragma unroll
            for (int r = 0; r < 3; ++r) {
                float a = dx == 0 ? P[r][0] : P[r][1];
                float bb = dx == 0 ? P[r][1] : P[r][2];
                h[r][j] = a + wx[j] * (bb - a);
            }
        }
#pragma unroll
        for (int i = 0; i < 4; ++i) {
            int dy = ry[i] - r0;   // 0 or 1
#pragma unroll
            for (int j = 0; j < 4; ++j) {
                float h0 = dy == 0 ? h[0][j] : h[1][j];
                float h1 = dy == 0 ? h[1][j] : h[2][j];
                acc[i][j] += h0 + wy[i] * (h1 - h0);
            }
        }
    }

    const float bt = sBtot;
    float* op = out + ((size_t)b * 512 + gy0) * 512 + gx0;
#pragma unroll
    for (int i = 0; i < 4; ++i) {
        float4 v;
        v.x = (acc[i][0] + bt) * (1.f / 3.f);
        v.y = (acc[i][1] + bt) * (1.f / 3.f);
        v.z = (acc[i][2] + bt) * (1.f / 3.f);
        v.w = (acc[i][3] + bt) * (1.f / 3.f);
        *(float4*)(op + (size_t)i * 512) = v;
    }
}

extern "C" void kernel_launch(void* const* d_in, const int* in_sizes, int n_in,
                              void* d_out, int out_size, void* d_ws, size_t ws_size,
                              hipStream_t stream) {
    (void)in_sizes; (void)n_in; (void)out_size; (void)ws_size;
    const float* x = (const float*)d_in[0];
    float* ws = (float*)d_ws;
    float* out = (float*)d_out;

    // Workspace layout (float offsets):
    float* pyr1 = ws;                  // 256^2*24 = 1572864
    float* pyr2 = ws + 1572864;        // 128^2*24 =  393216
    float* pyr3 = ws + 1966080;        //  64^2*24 =   98304
    float* dBase = ws + 2064384;       // d0..d6   = 2097024
    float* tileMin = ws + 4161408;     // 7680
    float* tileMax = ws + 4169088;     // 7680
    float* A = ws + 4176768;           // 168
    float* Bc = ws + 4176936;          // 168

    // Level 1 from raw x (initial _norm_pc is an affine no-op for the output)
    pyrdown_tiled<512, false, 0><<<NPLANES * 64, 256, 0, stream>>>(x, pyr1, nullptr, nullptr, nullptr);
    pyrdown_tiled<256, true, 0><<<NPLANES * 16, 256, 0, stream>>>(pyr1, pyr2, dBase + d_off(0), tileMin, tileMax);
    pyrdown_tiled<128, true, 1><<<NPLANES * 4, 256, 0, stream>>>(pyr2, pyr3, dBase + d_off(1), tileMin, tileMax);
    fused_small_kernel<<<NPLANES, 1024, 0, stream>>>(pyr3, dBase, tileMin, tileMax, A, Bc);
    final_kernel<<<8 * 64, 256, 0, stream>>>(dBase, A, Bc, out);
}

// Round 7
// 116.528 us; speedup vs baseline: 1.1462x; 1.0239x over previous
//
#include <hip/hip_runtime.h>
#include <math.h>

#define NPLANES 24   // B*C = 8*3
#define FINF 3.402823466e38f

__host__ __device__ __forceinline__ int d_off(int li) {
    // cumulative float offset of d-level li inside dBase (sizes 256^2..4^2 x24)
    return 2097152 - (2097152 >> (2 * li));
}

__device__ __forceinline__ int refl(int v, int S) {
    if (v < 0) v = -v;
    if (v >= S) v = 2 * S - 2 - v;
    return v;
}

// ---- wave-64 reductions ----
__device__ __forceinline__ float wmin64(float v) {
#pragma unroll
    for (int o = 32; o > 0; o >>= 1) v = fminf(v, __shfl_down(v, o, 64));
    return v;
}
__device__ __forceinline__ float wmax64(float v) {
#pragma unroll
    for (int o = 32; o > 0; o >>= 1) v = fmaxf(v, __shfl_down(v, o, 64));
    return v;
}
__device__ __forceinline__ float wsum64(float v) {
#pragma unroll
    for (int o = 32; o > 0; o >>= 1) v += __shfl_down(v, o, 64);
    return v;
}
// ---- block-1024 reductions (16 waves); all 1024 threads must call ----
__device__ __forceinline__ float bmin1024(float v, float* cross, int tid) {
    v = wmin64(v);
    if ((tid & 63) == 0) cross[tid >> 6] = v;
    __syncthreads();
    if (tid < 16) {
        float t = cross[tid];
#pragma unroll
        for (int o = 8; o > 0; o >>= 1) t = fminf(t, __shfl_down(t, o, 16));
        if (tid == 0) cross[0] = t;
    }
    __syncthreads();
    float r = cross[0];
    __syncthreads();
    return r;
}
__device__ __forceinline__ float bmax1024(float v, float* cross, int tid) {
    v = wmax64(v);
    if ((tid & 63) == 0) cross[tid >> 6] = v;
    __syncthreads();
    if (tid < 16) {
        float t = cross[tid];
#pragma unroll
        for (int o = 8; o > 0; o >>= 1) t = fmaxf(t, __shfl_down(t, o, 16));
        if (tid == 0) cross[0] = t;
    }
    __syncthreads();
    float r = cross[0];
    __syncthreads();
    return r;
}
__device__ __forceinline__ float bsum1024(float v, float* cross, int tid) {
    v = wsum64(v);
    if ((tid & 63) == 0) cross[tid >> 6] = v;
    __syncthreads();
    if (tid < 16) {
        float t = cross[tid];
#pragma unroll
        for (int o = 8; o > 0; o >>= 1) t += __shfl_down(t, o, 16);
        if (tid == 0) cross[0] = t;
    }
    __syncthreads();
    float r = cross[0];
    __syncthreads();
    return r;
}

// 6-tap separable collapsed pyrdown stencil on an LDS plane of size SxS.
__device__ __forceinline__ float stencil6(const float* s, int S, int i, int j) {
    const float w[6] = {1.f, 5.f, 10.f, 10.f, 5.f, 1.f};
    int rx[6];
#pragma unroll
    for (int b = 0; b < 6; ++b) rx[b] = refl(2 * j - 2 + b, S);
    float acc = 0.f;
#pragma unroll
    for (int a = 0; a < 6; ++a) {
        int ry = refl(2 * i - 2 + a, S);
        const float* rp = s + ry * S;
        float r = 0.f;
#pragma unroll
        for (int b = 0; b < 6; ++b) r += w[b] * rp[rx[b]];
        acc += w[a] * r;
    }
    return acc * (1.f / 1024.f);
}

// Tiled separable pyrdown, vectorized LDS passes. Block = 32x32 output tile.
// h-pass: 3x ds_read_b128 -> 4 outputs; v-pass: 6x ds_read_b128 -> 4 outputs
// + float4 global store. Same fp op ordering as the scalar version.
template <int IS, bool HAS_D>
__global__ __launch_bounds__(256) void pyrdown_tiled(const float* __restrict__ in,
                                                     float* __restrict__ out,
                                                     float* __restrict__ dout,
                                                     float* __restrict__ tileMin,
                                                     float* __restrict__ tileMax) {
    constexpr int SO = IS / 2;
    constexpr int TO = 32;            // output tile edge
    constexpr int TI = 2 * TO + 4;    // 68 staged input edge
    constexpr int TPA = SO / TO;      // output tiles per axis
    __shared__ float sIn[TI * TI];    // 4624
    __shared__ float sH[TI * TO];     // 2176
    __shared__ float sOut[TO * TO];   // 1024
    __shared__ float sD[HAS_D ? 64 * 65 : 1];
    __shared__ float rmn[HAS_D ? 256 : 1], rmx[HAS_D ? 256 : 1];

    const int tid = threadIdx.x;
    const int p = blockIdx.x / (TPA * TPA);
    const int t = blockIdx.x % (TPA * TPA);
    const int ty = t / TPA, tx = t % TPA;
    const int oy = ty * TO, ox = tx * TO;
    const int iy = 2 * oy - 2, ix = 2 * ox - 2;
    const float* ip = in + (size_t)p * IS * IS;

    for (int k = tid; k < TI * TI; k += 256) {
        int r = k / TI, c = k - r * TI;
        sIn[k] = ip[refl(iy + r, IS) * IS + refl(ix + c, IS)];
    }
    __syncthreads();

    // h-pass: task = (row r, quad jq); reads sIn[r][8jq..8jq+11] (16B aligned)
    for (int k = tid; k < TI * 8; k += 256) {
        int r = k >> 3, jq = k & 7;
        const float4* rp = (const float4*)(sIn + r * TI + 8 * jq);
        float4 v0 = rp[0], v1 = rp[1], v2 = rp[2];
        float4 o;
        o.x = v0.x + 5.f * v0.y + 10.f * v0.z + 10.f * v0.w + 5.f * v1.x + v1.y;
        o.y = v0.z + 5.f * v0.w + 10.f * v1.x + 10.f * v1.y + 5.f * v1.z + v1.w;
        o.z = v1.x + 5.f * v1.y + 10.f * v1.z + 10.f * v1.w + 5.f * v2.x + v2.y;
        o.w = v1.z + 5.f * v1.w + 10.f * v2.x + 10.f * v2.y + 5.f * v2.z + v2.w;
        *(float4*)(sH + r * TO + 4 * jq) = o;
    }
    __syncthreads();

    // v-pass: one task/thread: i = tid>>3, jq = tid&7
    {
        int i = tid >> 3, jq = tid & 7;
        const float* base = sH + (2 * i) * TO + 4 * jq;
        float4 r0 = *(const float4*)(base);
        float4 r1 = *(const float4*)(base + TO);
        float4 r2 = *(const float4*)(base + 2 * TO);
        float4 r3 = *(const float4*)(base + 3 * TO);
        float4 r4 = *(const float4*)(base + 4 * TO);
        float4 r5 = *(const float4*)(base + 5 * TO);
        float4 o;
        o.x = (r0.x + 5.f * r1.x + 10.f * r2.x + 10.f * r3.x + 5.f * r4.x + r5.x) * (1.f / 1024.f);
        o.y = (r0.y + 5.f * r1.y + 10.f * r2.y + 10.f * r3.y + 5.f * r4.y + r5.y) * (1.f / 1024.f);
        o.z = (r0.z + 5.f * r1.z + 10.f * r2.z + 10.f * r3.z + 5.f * r4.z + r5.z) * (1.f / 1024.f);
        o.w = (r0.w + 5.f * r1.w + 10.f * r2.w + 10.f * r3.w + 5.f * r4.w + r5.w) * (1.f / 1024.f);
        *(float4*)(sOut + i * TO + 4 * jq) = o;
        *(float4*)(out + (size_t)p * SO * SO + (size_t)(oy + i) * SO + ox + 4 * jq) = o;
    }

    if (HAS_D) {
        __syncthreads();
        float* dp = dout + (size_t)p * IS * IS;
        for (int k = tid; k < 4096; k += 256) {
            int yy = k >> 6, xx = k & 63;
            float dv = fabsf(sIn[(yy + 2) * TI + xx + 2] - sOut[(yy >> 1) * TO + (xx >> 1)]);
            sD[yy * 65 + xx] = dv;
            dp[(size_t)(2 * oy + yy) * IS + 2 * ox + xx] = dv;
        }
        __syncthreads();
        int s = tid >> 4, r = tid & 15;
        int tr = s >> 2, tc = s & 3;
        const float* rowp = sD + (tr * 16 + r) * 65 + tc * 16;
        float mn = FINF, mx = -FINF;
#pragma unroll
        for (int c = 0; c < 16; ++c) {
            float v = rowp[c];
            mn = fminf(mn, v); mx = fmaxf(mx, v);
        }
        rmn[tid] = mn; rmx[tid] = mx;
        __syncthreads();
        for (int st = 8; st > 0; st >>= 1) {
            if (r < st) {
                rmn[tid] = fminf(rmn[tid], rmn[tid + st]);
                rmx[tid] = fmaxf(rmx[tid], rmx[tid + st]);
            }
            __syncthreads();
        }
        if (r == 0) {
            constexpr int TA = IS / 16;
            int gidx = p * TA * TA + (ty * 4 + tr) * TA + (tx * 4 + tc);
            tileMin[gidx] = rmn[tid];
            tileMax[gidx] = rmx[tid];
        }
    }
}

// One block (1024 threads) per plane: pyr2 -> pyr3 (separable, LDS-only, never
// hits HBM), d1 float4-wide in-place + full li=1 stats, then pyr4..pyr8 chain
// + d2..d6 + li=2..6 stats + li=0 reduce from tile stats.
__global__ __launch_bounds__(1024) void fused_small_kernel(const float* __restrict__ pyr2,
                                                           float* __restrict__ dBase,
                                                           const float* __restrict__ tileMin,
                                                           const float* __restrict__ tileMax,
                                                           float* __restrict__ A,
                                                           float* __restrict__ B) {
    __shared__ float sP2[16384];   // 64 KB; becomes d1 in place
    __shared__ float sHbuf[8192];  // 32 KB h-pass buffer; chain buffers alias it
    __shared__ float sP3[4096];    // 16 KB
    __shared__ float cross[16];
    __shared__ float strip[1024];
    __shared__ float tmaxLds[64];
    float* sd2 = sHbuf;            // 4096
    float* sp4 = sHbuf + 4096;     // 1024
    float* sd3 = sHbuf + 5120;     // 1024
    float* sp5 = sHbuf + 6144;     // 256
    float* sd4 = sHbuf + 6400;     // 256
    float* sp6 = sHbuf + 6656;     // 64
    float* sd5 = sHbuf + 6720;     // 64
    float* sp7 = sHbuf + 6784;     // 16
    float* sd6 = sHbuf + 6800;     // 16
    const int tid = threadIdx.x;
    const int p = blockIdx.x;

    // load pyr2 plane (vector)
    {
        const float4* gp = (const float4*)(pyr2 + (size_t)p * 16384);
        float4* sv = (float4*)sP2;
        for (int k = tid; k < 4096; k += 1024) sv[k] = gp[k];
    }
    __syncthreads();
    // h-pass: 128 rows x 64 out-cols
    for (int k = tid; k < 8192; k += 1024) {
        int r = k >> 6, c = k & 63;
        int b0 = 2 * c - 2;
        const float* rp = sP2 + r * 128;
        sHbuf[k] = rp[refl(b0, 128)] + 5.f * rp[refl(b0 + 1, 128)] + 10.f * rp[refl(b0 + 2, 128)] +
                   10.f * rp[refl(b0 + 3, 128)] + 5.f * rp[refl(b0 + 4, 128)] + rp[refl(b0 + 5, 128)];
    }
    __syncthreads();
    // v-pass -> sP3 (64x64)
    for (int k = tid; k < 4096; k += 1024) {
        int r3 = k >> 6, c = k & 63;
        int b0 = 2 * r3 - 2;
        float s = sHbuf[refl(b0, 128) * 64 + c] + 5.f * sHbuf[refl(b0 + 1, 128) * 64 + c] +
                  10.f * sHbuf[refl(b0 + 2, 128) * 64 + c] + 10.f * sHbuf[refl(b0 + 3, 128) * 64 + c] +
                  5.f * sHbuf[refl(b0 + 4, 128) * 64 + c] + sHbuf[refl(b0 + 5, 128) * 64 + c];
        sP3[k] = s * (1.f / 1024.f);
    }
    __syncthreads();
    // d1 float4-wide, in place over sP2, + global write; min/max in registers
    float mnReg = FINF, mxReg = -FINF;
    {
        float4* d1g = (float4*)(dBase + d_off(1) + (size_t)p * 16384);
        float4* sv = (float4*)sP2;
        for (int k = tid; k < 4096; k += 1024) {
            int row = k >> 5, c4 = k & 31;
            float4 v = sv[k];
            float2 o = *(const float2*)(sP3 + (row >> 1) * 64 + 2 * c4);
            float4 dv;
            dv.x = fabsf(v.x - o.x);
            dv.y = fabsf(v.y - o.x);
            dv.z = fabsf(v.z - o.y);
            dv.w = fabsf(v.w - o.y);
            sv[k] = dv;
            d1g[k] = dv;
            mnReg = fminf(mnReg, fminf(fminf(dv.x, dv.y), fminf(dv.z, dv.w)));
            mxReg = fmaxf(mxReg, fmaxf(fmaxf(dv.x, dv.y), fmaxf(dv.z, dv.w)));
        }
    }
    __syncthreads();
    // li=1 stats: plane min/max from registers; tile maxima (64 tiles of 16x16)
    {
        float mn = bmin1024(mnReg, cross, tid);
        float mx = bmax1024(mxReg, cross, tid);
        {
            int s = tid >> 4, r = tid & 15;
            int tr = s >> 3, tc = s & 7;
            const float4* rowp = (const float4*)(sP2 + (tr * 16 + r) * 128 + tc * 16);
            float sm = -FINF;
#pragma unroll
            for (int q = 0; q < 4; ++q) {
                float4 v = rowp[q];
                sm = fmaxf(sm, fmaxf(fmaxf(v.x, v.y), fmaxf(v.z, v.w)));
            }
            strip[tid] = sm;
        }
        __syncthreads();
        if (tid < 64) {
            float tm = -FINF;
            for (int r = 0; r < 16; ++r) tm = fmaxf(tm, strip[tid * 16 + r]);
            tmaxLds[tid] = tm;
        }
        __syncthreads();
        float su = (tid < 64 && (tid >> 3) < 7 && (tid & 7) < 7) ? tmaxLds[tid] : 0.f;
        float sum = bsum1024(su, cross, tid);
        if (tid == 0) {
            float inv = 1.f / (mx - mn);
            float lm = (sum * (1.f / 49.f) - mn) * inv;
            float g = (1.f - lm) * (1.f - lm);
            A[1 * NPLANES + p] = g * inv;
            B[1 * NPLANES + p] = -mn * g * inv;
        }
    }
    // ---- li=0 reduce from tile stats (256 tiles, interior 15x15) ----
    {
        float tmn = (tid < 256) ? tileMin[p * 256 + tid] : FINF;
        float tmx = (tid < 256) ? tileMax[p * 256 + tid] : -FINF;
        float mn = bmin1024(tmn, cross, tid);
        float mx = bmax1024(tmx, cross, tid);
        float su = (tid < 256 && (tid >> 4) < 15 && (tid & 15) < 15) ? tmx : 0.f;
        float sum = bsum1024(su, cross, tid);
        if (tid == 0) {
            float inv = 1.f / (mx - mn);
            float lm = (sum * (1.f / 225.f) - mn) * inv;
            float g = (1.f - lm) * (1.f - lm);
            A[0 * NPLANES + p] = g * inv;
            B[0 * NPLANES + p] = -mn * g * inv;
        }
    }
    __syncthreads();   // sHbuf about to be reused as chain buffers

    // pyr4 (32x32) + d2 (64x64): one output per thread
    {
        float* d2g = dBase + d_off(2) + (size_t)p * 4096;
        int i = tid >> 5, j = tid & 31;
        float v = stencil6(sP3, 64, i, j);
        sp4[tid] = v;
#pragma unroll
        for (int di = 0; di < 2; ++di)
#pragma unroll
            for (int dj = 0; dj < 2; ++dj) {
                int y = 2 * i + di, x = 2 * j + dj;
                float dv = fabsf(sP3[y * 64 + x] - v);
                sd2[y * 64 + x] = dv;
                d2g[y * 64 + x] = dv;
            }
    }
    __syncthreads();
    // pyr5 (16x16) + d3 (32x32)
    if (tid < 256) {
        int i = tid >> 4, j = tid & 15;
        float v = stencil6(sp4, 32, i, j);
        sp5[tid] = v;
        float* d3g = dBase + d_off(3) + (size_t)p * 1024;
#pragma unroll
        for (int di = 0; di < 2; ++di)
#pragma unroll
            for (int dj = 0; dj < 2; ++dj) {
                int y = 2 * i + di, x = 2 * j + dj;
                float dv = fabsf(sp4[y * 32 + x] - v);
                sd3[y * 32 + x] = dv;
                d3g[y * 32 + x] = dv;
            }
    }
    __syncthreads();
    // pyr6 (8x8) + d4 (16x16)
    if (tid < 64) {
        int i = tid >> 3, j = tid & 7;
        float v = stencil6(sp5, 16, i, j);
        sp6[tid] = v;
        float* d4g = dBase + d_off(4) + (size_t)p * 256;
#pragma unroll
        for (int di = 0; di < 2; ++di)
#pragma unroll
            for (int dj = 0; dj < 2; ++dj) {
                int y = 2 * i + di, x = 2 * j + dj;
                float dv = fabsf(sp5[y * 16 + x] - v);
                sd4[y * 16 + x] = dv;
                d4g[y * 16 + x] = dv;
            }
    }
    __syncthreads();
    // pyr7 (4x4) + d5 (8x8)
    if (tid < 16) {
        int i = tid >> 2, j = tid & 3;
        float v = stencil6(sp6, 8, i, j);
        sp7[tid] = v;
        float* d5g = dBase + d_off(5) + (size_t)p * 64;
#pragma unroll
        for (int di = 0; di < 2; ++di)
#pragma unroll
            for (int dj = 0; dj < 2; ++dj) {
                int y = 2 * i + di, x = 2 * j + dj;
                float dv = fabsf(sp6[y * 8 + x] - v);
                sd5[y * 8 + x] = dv;
                d5g[y * 8 + x] = dv;
            }
    }
    __syncthreads();
    // pyr8 (2x2) + d6 (4x4)
    if (tid < 4) {
        int i = tid >> 1, j = tid & 1;
        float v = stencil6(sp7, 4, i, j);
        float* d6g = dBase + d_off(6) + (size_t)p * 16;
#pragma unroll
        for (int di = 0; di < 2; ++di)
#pragma unroll
            for (int dj = 0; dj < 2; ++dj) {
                int y = 2 * i + di, x = 2 * j + dj;
                float dv = fabsf(sp7[y * 4 + x] - v);
                sd6[y * 4 + x] = dv;
                d6g[y * 4 + x] = dv;
            }
    }
    __syncthreads();

    // ---- stats li=2 (S=64, interior 3x3 of 4x4 tiles) ----
    {
        float4 q = ((const float4*)sd2)[tid];
        float mn = fminf(fminf(q.x, q.y), fminf(q.z, q.w));
        float mx = fmaxf(fmaxf(q.x, q.y), fmaxf(q.z, q.w));
        mn = bmin1024(mn, cross, tid);
        mx = bmax1024(mx, cross, tid);
        if (tid < 256) {
            int t = tid >> 4, r = tid & 15;
            int ty = t >> 2, tx = t & 3;
            const float* rowp = sd2 + (ty * 16 + r) * 64 + tx * 16;
            float sm = -FINF;
#pragma unroll
            for (int c = 0; c < 16; ++c) sm = fmaxf(sm, rowp[c]);
            strip[tid] = sm;
        }
        __syncthreads();
        if (tid < 16) {
            float tm = -FINF;
            for (int r = 0; r < 16; ++r) tm = fmaxf(tm, strip[tid * 16 + r]);
            tmaxLds[tid] = tm;
        }
        __syncthreads();
        if (tid == 0) {
            float s = 0.f;
            for (int ty = 0; ty < 3; ++ty)
                for (int tx = 0; tx < 3; ++tx) s += tmaxLds[ty * 4 + tx];
            float inv = 1.f / (mx - mn);
            float lm = (s * (1.f / 9.f) - mn) * inv;
            float g = (1.f - lm) * (1.f - lm);
            A[2 * NPLANES + p] = g * inv;
            B[2 * NPLANES + p] = -mn * g * inv;
        }
        __syncthreads();
    }
    // ---- stats li=3 (S=32, single interior 16x16 tile) ----
    {
        float v = sd3[tid];
        float mn = bmin1024(v, cross, tid);
        float mx = bmax1024(v, cross, tid);
        float e = (tid < 256) ? sd3[(tid >> 4) * 32 + (tid & 15)] : -FINF;
        float tm = bmax1024(e, cross, tid);
        if (tid == 0) {
            float inv = 1.f / (mx - mn);
            float lm = (tm - mn) * inv;
            float g = (1.f - lm) * (1.f - lm);
            A[3 * NPLANES + p] = g * inv;
            B[3 * NPLANES + p] = -mn * g * inv;
        }
    }
    // ---- stats li=4,5,6 (lm=0) ----
    {
        float v = (tid < 256) ? sd4[tid] : FINF;
        float mn = bmin1024(v, cross, tid);
        v = (tid < 256) ? sd4[tid] : -FINF;
        float mx = bmax1024(v, cross, tid);
        if (tid == 0) {
            float inv = 1.f / (mx - mn);
            A[4 * NPLANES + p] = inv; B[4 * NPLANES + p] = -mn * inv;
        }
    }
    {
        float v = (tid < 64) ? sd5[tid] : FINF;
        float mn = bmin1024(v, cross, tid);
        v = (tid < 64) ? sd5[tid] : -FINF;
        float mx = bmax1024(v, cross, tid);
        if (tid == 0) {
            float inv = 1.f / (mx - mn);
            A[5 * NPLANES + p] = inv; B[5 * NPLANES + p] = -mn * inv;
        }
    }
    {
        float v = (tid < 16) ? sd6[tid] : FINF;
        float mn = bmin1024(v, cross, tid);
        v = (tid < 16) ? sd6[tid] : -FINF;
        float mx = bmax1024(v, cross, tid);
        if (tid == 0) {
            float inv = 1.f / (mx - mn);
            A[6 * NPLANES + p] = inv; B[6 * NPLANES + p] = -mn * inv;
        }
    }
}

// Tiled final gather, register-patch bilerp (R6-verified).
__global__ __launch_bounds__(256) void final_kernel(const float* __restrict__ dBase,
                                                    const float* __restrict__ A,
                                                    const float* __restrict__ Bc,
                                                    float* __restrict__ out) {
    __shared__ float patch[1700];
    __shared__ float sBtot;
    const int tid = threadIdx.x;
    const int b = blockIdx.x >> 6;
    const int tile = blockIdx.x & 63;
    const int yb = (tile >> 3) << 6;
    const int xb = (tile & 7) << 6;

    if (tid == 0) {
        float s = 0.f;
        for (int k = 0; k < 7; ++k)
            for (int c = 0; c < 3; ++c) s += Bc[k * NPLANES + b * 3 + c];
        sBtot = s;
    }

    const int dims[7] = {34, 18, 10, 6, 4, 3, 3};
    const int lofs[7] = {0, 1156, 1480, 1580, 1616, 1632, 1641};
    int baseY[7], baseX[7];
#pragma unroll
    for (int li = 0; li < 7; ++li) {
        const int S = 256 >> li;
        const float s = 1.f / (float)(2 << li);
        baseY[li] = (int)floorf((yb + 0.5f) * s - 0.5f);
        baseX[li] = (int)floorf((xb + 0.5f) * s - 0.5f);
        const int dim = dims[li];
        const int n = dim * dim;
        const float* d0p = dBase + d_off(li) + (size_t)(b * 3) * S * S;
        const float* d1p = d0p + S * S;
        const float* d2p = d1p + S * S;
        const float A0 = A[li * NPLANES + b * 3 + 0];
        const float A1 = A[li * NPLANES + b * 3 + 1];
        const float A2 = A[li * NPLANES + b * 3 + 2];
        for (int k = tid; k < n; k += 256) {
            int r = k / dim, c = k - r * dim;
            int sr = min(max(baseY[li] + r, 0), S - 1);
            int sc = min(max(baseX[li] + c, 0), S - 1);
            int si = sr * S + sc;
            patch[lofs[li] + k] = A0 * d0p[si] + A1 * d1p[si] + A2 * d2p[si];
        }
    }
    __syncthreads();

    const int ty = tid >> 4, tx = tid & 15;
    const int gy0 = yb + (ty << 2), gx0 = xb + (tx << 2);
    float acc[4][4];
#pragma unroll
    for (int i = 0; i < 4; ++i)
#pragma unroll
        for (int j = 0; j < 4; ++j) acc[i][j] = 0.f;

    // ---- level 0 (scale 1/2): 4x4 register patch ----
    {
        const int dim = 34;
        float wy[4], wx[4];
        int ry[4], cx[4];
#pragma unroll
        for (int k = 0; k < 4; ++k) {
            float fy = (gy0 + k + 0.5f) * 0.5f - 0.5f;
            float fl = floorf(fy);
            wy[k] = fy - fl; ry[k] = (int)fl - baseY[0];
            float fx = (gx0 + k + 0.5f) * 0.5f - 0.5f;
            fl = floorf(fx);
            wx[k] = fx - fl; cx[k] = (int)fl - baseX[0];
        }
        const int r0 = ry[0], c0 = cx[0];
        const float* pp = patch + r0 * dim + c0;
        float P[4][4];
#pragma unroll
        for (int r = 0; r < 4; ++r)
#pragma unroll
            for (int c = 0; c < 4; ++c) P[r][c] = pp[r * dim + c];
        float h[4][4];
#pragma unroll
        for (int j = 0; j < 4; ++j) {
            int dx = cx[j] - c0;
#pragma unroll
            for (int r = 0; r < 4; ++r) {
                float a = dx == 0 ? P[r][0] : (dx == 1 ? P[r][1] : P[r][2]);
                float bb = dx == 0 ? P[r][1] : (dx == 1 ? P[r][2] : P[r][3]);
                h[r][j] = a + wx[j] * (bb - a);
            }
        }
#pragma unroll
        for (int i = 0; i < 4; ++i) {
            int dy = ry[i] - r0;
#pragma unroll
            for (int j = 0; j < 4; ++j) {
                float h0 = dy == 0 ? h[0][j] : (dy == 1 ? h[1][j] : h[2][j]);
                float h1 = dy == 0 ? h[1][j] : (dy == 1 ? h[2][j] : h[3][j]);
                acc[i][j] += h0 + wy[i] * (h1 - h0);
            }
        }
    }
    // ---- levels 1..6 (scale <= 1/4): 3x3 register patch ----
#pragma unroll
    for (int li = 1; li < 7; ++li) {
        const int dim = dims[li];
        const float* P0 = patch + lofs[li];
        const float s = 1.f / (float)(2 << li);
        float wy[4], wx[4];
        int ry[4], cx[4];
#pragma unroll
        for (int k = 0; k < 4; ++k) {
            float fy = (gy0 + k + 0.5f) * s - 0.5f;
            float fl = floorf(fy);
            wy[k] = fy - fl; ry[k] = (int)fl - baseY[li];
            float fx = (gx0 + k + 0.5f) * s - 0.5f;
            fl = floorf(fx);
            wx[k] = fx - fl; cx[k] = (int)fl - baseX[li];
        }
        const int r0 = ry[0], c0 = cx[0];
        const float* pp = P0 + r0 * dim + c0;
        float P[3][3];
#pragma unroll
        for (int r = 0; r < 3; ++r)
#pragma unroll
            for (int c = 0; c < 3; ++c) P[r][c] = pp[r * dim + c];
        float h[3][4];
#pragma unroll
        for (int j = 0; j < 4; ++j) {
            int dx = cx[j] - c0;   // 0 or 1
#pragma unroll
            for (int r = 0; r < 3; ++r) {
                float a = dx == 0 ? P[r][0] : P[r][1];
                float bb = dx == 0 ? P[r][1] : P[r][2];
                h[r][j] = a + wx[j] * (bb - a);
            }
        }
#pragma unroll
        for (int i = 0; i < 4; ++i) {
            int dy = ry[i] - r0;   // 0 or 1
#pragma unroll
            for (int j = 0; j < 4; ++j) {
                float h0 = dy == 0 ? h[0][j] : h[1][j];
                float h1 = dy == 0 ? h[1][j] : h[2][j];
                acc[i][j] += h0 + wy[i] * (h1 - h0);
            }
        }
    }

    const float bt = sBtot;
    float* op = out + ((size_t)b * 512 + gy0) * 512 + gx0;
#pragma unroll
    for (int i = 0; i < 4; ++i) {
        float4 v;
        v.x = (acc[i][0] + bt) * (1.f / 3.f);
        v.y = (acc[i][1] + bt) * (1.f / 3.f);
        v.z = (acc[i][2] + bt) * (1.f / 3.f);
        v.w = (acc[i][3] + bt) * (1.f / 3.f);
        *(float4*)(op + (size_t)i * 512) = v;
    }
}

extern "C" void kernel_launch(void* const* d_in, const int* in_sizes, int n_in,
                              void* d_out, int out_size, void* d_ws, size_t ws_size,
                              hipStream_t stream) {
    (void)in_sizes; (void)n_in; (void)out_size; (void)ws_size;
    const float* x = (const float*)d_in[0];
    float* ws = (float*)d_ws;
    float* out = (float*)d_out;

    // Workspace layout (float offsets):
    float* pyr1 = ws;                  // 256^2*24 = 1572864
    float* pyr2 = ws + 1572864;        // 128^2*24 =  393216
    float* dBase = ws + 1966080;       // d0..d6   = 2097024
    float* tileMin = ws + 4063104;     // 6144 (li=0 only)
    float* tileMax = ws + 4069248;     // 6144
    float* A = ws + 4075392;           // 168
    float* Bc = ws + 4075560;          // 168

    // Level 1 from raw x (initial _norm_pc is an affine no-op for the output)
    pyrdown_tiled<512, false><<<NPLANES * 64, 256, 0, stream>>>(x, pyr1, nullptr, nullptr, nullptr);
    pyrdown_tiled<256, true><<<NPLANES * 16, 256, 0, stream>>>(pyr1, pyr2, dBase + d_off(0), tileMin, tileMax);
    fused_small_kernel<<<NPLANES, 1024, 0, stream>>>(pyr2, dBase, tileMin, tileMax, A, Bc);
    final_kernel<<<8 * 64, 256, 0, stream>>>(dBase, A, Bc, out);
}

// Round 8
// 109.424 us; speedup vs baseline: 1.2206x; 1.0649x over previous
//
#include <hip/hip_runtime.h>
#include <math.h>

#define NPLANES 24   // B*C = 8*3
#define FINF 3.402823466e38f

__host__ __device__ __forceinline__ int d_off(int li) {
    // cumulative float offset of d-level li inside dBase (sizes 256^2..4^2 x24)
    return 2097152 - (2097152 >> (2 * li));
}

__device__ __forceinline__ int refl(int v, int S) {
    if (v < 0) v = -v;
    if (v >= S) v = 2 * S - 2 - v;
    return v;
}

// ---- wave-64 shuffle reductions (no LDS, no barriers) ----
__device__ __forceinline__ void wminmax64(float& mn, float& mx) {
#pragma unroll
    for (int o = 32; o > 0; o >>= 1) {
        mn = fminf(mn, __shfl_xor(mn, o, 64));
        mx = fmaxf(mx, __shfl_xor(mx, o, 64));
    }
}
__device__ __forceinline__ float wsumx64(float v) {
#pragma unroll
    for (int o = 32; o > 0; o >>= 1) v += __shfl_xor(v, o, 64);
    return v;
}

// 6-tap separable collapsed pyrdown stencil on an LDS plane of size SxS.
__device__ __forceinline__ float stencil6(const float* s, int S, int i, int j) {
    const float w[6] = {1.f, 5.f, 10.f, 10.f, 5.f, 1.f};
    int rx[6];
#pragma unroll
    for (int b = 0; b < 6; ++b) rx[b] = refl(2 * j - 2 + b, S);
    float acc = 0.f;
#pragma unroll
    for (int a = 0; a < 6; ++a) {
        int ry = refl(2 * i - 2 + a, S);
        const float* rp = s + ry * S;
        float r = 0.f;
#pragma unroll
        for (int b = 0; b < 6; ++b) r += w[b] * rp[rx[b]];
        acc += w[a] * r;
    }
    return acc * (1.f / 1024.f);
}

// Tiled separable pyrdown, vectorized LDS passes (R7-verified).
template <int IS, bool HAS_D>
__global__ __launch_bounds__(256) void pyrdown_tiled(const float* __restrict__ in,
                                                     float* __restrict__ out,
                                                     float* __restrict__ dout,
                                                     float* __restrict__ tileMin,
                                                     float* __restrict__ tileMax) {
    constexpr int SO = IS / 2;
    constexpr int TO = 32;
    constexpr int TI = 2 * TO + 4;    // 68
    constexpr int TPA = SO / TO;
    __shared__ float sIn[TI * TI];
    __shared__ float sH[TI * TO];
    __shared__ float sOut[TO * TO];
    __shared__ float sD[HAS_D ? 64 * 65 : 1];
    __shared__ float rmn[HAS_D ? 256 : 1], rmx[HAS_D ? 256 : 1];

    const int tid = threadIdx.x;
    const int p = blockIdx.x / (TPA * TPA);
    const int t = blockIdx.x % (TPA * TPA);
    const int ty = t / TPA, tx = t % TPA;
    const int oy = ty * TO, ox = tx * TO;
    const int iy = 2 * oy - 2, ix = 2 * ox - 2;
    const float* ip = in + (size_t)p * IS * IS;

    for (int k = tid; k < TI * TI; k += 256) {
        int r = k / TI, c = k - r * TI;
        sIn[k] = ip[refl(iy + r, IS) * IS + refl(ix + c, IS)];
    }
    __syncthreads();

    for (int k = tid; k < TI * 8; k += 256) {
        int r = k >> 3, jq = k & 7;
        const float4* rp = (const float4*)(sIn + r * TI + 8 * jq);
        float4 v0 = rp[0], v1 = rp[1], v2 = rp[2];
        float4 o;
        o.x = v0.x + 5.f * v0.y + 10.f * v0.z + 10.f * v0.w + 5.f * v1.x + v1.y;
        o.y = v0.z + 5.f * v0.w + 10.f * v1.x + 10.f * v1.y + 5.f * v1.z + v1.w;
        o.z = v1.x + 5.f * v1.y + 10.f * v1.z + 10.f * v1.w + 5.f * v2.x + v2.y;
        o.w = v1.z + 5.f * v1.w + 10.f * v2.x + 10.f * v2.y + 5.f * v2.z + v2.w;
        *(float4*)(sH + r * TO + 4 * jq) = o;
    }
    __syncthreads();

    {
        int i = tid >> 3, jq = tid & 7;
        const float* base = sH + (2 * i) * TO + 4 * jq;
        float4 r0 = *(const float4*)(base);
        float4 r1 = *(const float4*)(base + TO);
        float4 r2 = *(const float4*)(base + 2 * TO);
        float4 r3 = *(const float4*)(base + 3 * TO);
        float4 r4 = *(const float4*)(base + 4 * TO);
        float4 r5 = *(const float4*)(base + 5 * TO);
        float4 o;
        o.x = (r0.x + 5.f * r1.x + 10.f * r2.x + 10.f * r3.x + 5.f * r4.x + r5.x) * (1.f / 1024.f);
        o.y = (r0.y + 5.f * r1.y + 10.f * r2.y + 10.f * r3.y + 5.f * r4.y + r5.y) * (1.f / 1024.f);
        o.z = (r0.z + 5.f * r1.z + 10.f * r2.z + 10.f * r3.z + 5.f * r4.z + r5.z) * (1.f / 1024.f);
        o.w = (r0.w + 5.f * r1.w + 10.f * r2.w + 10.f * r3.w + 5.f * r4.w + r5.w) * (1.f / 1024.f);
        *(float4*)(sOut + i * TO + 4 * jq) = o;
        *(float4*)(out + (size_t)p * SO * SO + (size_t)(oy + i) * SO + ox + 4 * jq) = o;
    }

    if (HAS_D) {
        __syncthreads();
        float* dp = dout + (size_t)p * IS * IS;
        for (int k = tid; k < 4096; k += 256) {
            int yy = k >> 6, xx = k & 63;
            float dv = fabsf(sIn[(yy + 2) * TI + xx + 2] - sOut[(yy >> 1) * TO + (xx >> 1)]);
            sD[yy * 65 + xx] = dv;
            dp[(size_t)(2 * oy + yy) * IS + 2 * ox + xx] = dv;
        }
        __syncthreads();
        int s = tid >> 4, r = tid & 15;
        int tr = s >> 2, tc = s & 3;
        const float* rowp = sD + (tr * 16 + r) * 65 + tc * 16;
        float mn = FINF, mx = -FINF;
#pragma unroll
        for (int c = 0; c < 16; ++c) {
            float v = rowp[c];
            mn = fminf(mn, v); mx = fmaxf(mx, v);
        }
        rmn[tid] = mn; rmx[tid] = mx;
        __syncthreads();
        for (int st = 8; st > 0; st >>= 1) {
            if (r < st) {
                rmn[tid] = fminf(rmn[tid], rmn[tid + st]);
                rmx[tid] = fmaxf(rmx[tid], rmx[tid + st]);
            }
            __syncthreads();
        }
        if (r == 0) {
            constexpr int TA = IS / 16;
            int gidx = p * TA * TA + (ty * 4 + tr) * TA + (tx * 4 + tc);
            tileMin[gidx] = rmn[tid];
            tileMax[gidx] = rmx[tid];
        }
    }
}

// One block (1024 threads) per plane. Barrier-light: parallel front (4 barriers),
// all-thread pyr4+d2 (1 barrier), then wave-specialized stages (2 barriers):
//   B: wave0 = pyr5..8 chain solo (wave-internal LDS, no barriers)
//      wave1 = li=1 stats solo; wave2 = li=0 tile reduce solo
//   C: waves 0..4 = li=2..6 stats, one level per wave, shuffle-only.
__global__ __launch_bounds__(1024) void fused_small_kernel(const float* __restrict__ pyr2,
                                                           float* __restrict__ dBase,
                                                           const float* __restrict__ tileMin,
                                                           const float* __restrict__ tileMax,
                                                           float* __restrict__ A,
                                                           float* __restrict__ B) {
    __shared__ float sP2[16384];   // 64 KB; becomes d1 in place
    __shared__ float sHbuf[8192];  // h-pass buffer; chain buffers alias it
    __shared__ float sP3[4096];
    float* sd2 = sHbuf;            // 4096
    float* sp4 = sHbuf + 4096;     // 1024
    float* sd3 = sHbuf + 5120;     // 1024
    float* sp5 = sHbuf + 6144;     // 256
    float* sd4 = sHbuf + 6400;     // 256
    float* sp6 = sHbuf + 6656;     // 64
    float* sd5 = sHbuf + 6720;     // 64
    float* sp7 = sHbuf + 6784;     // 16
    float* sd6 = sHbuf + 6800;     // 16
    const int tid = threadIdx.x;
    const int p = blockIdx.x;

    {
        const float4* gp = (const float4*)(pyr2 + (size_t)p * 16384);
        float4* sv = (float4*)sP2;
        for (int k = tid; k < 4096; k += 1024) sv[k] = gp[k];
    }
    __syncthreads();
    // h-pass: 128 rows x 64 out-cols
    for (int k = tid; k < 8192; k += 1024) {
        int r = k >> 6, c = k & 63;
        int b0 = 2 * c - 2;
        const float* rp = sP2 + r * 128;
        sHbuf[k] = rp[refl(b0, 128)] + 5.f * rp[refl(b0 + 1, 128)] + 10.f * rp[refl(b0 + 2, 128)] +
                   10.f * rp[refl(b0 + 3, 128)] + 5.f * rp[refl(b0 + 4, 128)] + rp[refl(b0 + 5, 128)];
    }
    __syncthreads();
    // v-pass -> sP3 (64x64)
    for (int k = tid; k < 4096; k += 1024) {
        int r3 = k >> 6, c = k & 63;
        int b0 = 2 * r3 - 2;
        float s = sHbuf[refl(b0, 128) * 64 + c] + 5.f * sHbuf[refl(b0 + 1, 128) * 64 + c] +
                  10.f * sHbuf[refl(b0 + 2, 128) * 64 + c] + 10.f * sHbuf[refl(b0 + 3, 128) * 64 + c] +
                  5.f * sHbuf[refl(b0 + 4, 128) * 64 + c] + sHbuf[refl(b0 + 5, 128) * 64 + c];
        sP3[k] = s * (1.f / 1024.f);
    }
    __syncthreads();
    // d1 float4-wide, in place over sP2, + global write
    {
        float4* d1g = (float4*)(dBase + d_off(1) + (size_t)p * 16384);
        float4* sv = (float4*)sP2;
        for (int k = tid; k < 4096; k += 1024) {
            int row = k >> 5, c4 = k & 31;
            float4 v = sv[k];
            float2 o = *(const float2*)(sP3 + (row >> 1) * 64 + 2 * c4);
            float4 dv;
            dv.x = fabsf(v.x - o.x);
            dv.y = fabsf(v.y - o.x);
            dv.z = fabsf(v.z - o.y);
            dv.w = fabsf(v.w - o.y);
            sv[k] = dv;
            d1g[k] = dv;
        }
    }
    __syncthreads();
    // stage A: pyr4 (32x32) + d2 (64x64), one output per thread
    {
        float* d2g = dBase + d_off(2) + (size_t)p * 4096;
        int i = tid >> 5, j = tid & 31;
        float v = stencil6(sP3, 64, i, j);
        sp4[tid] = v;
#pragma unroll
        for (int di = 0; di < 2; ++di)
#pragma unroll
            for (int dj = 0; dj < 2; ++dj) {
                int y = 2 * i + di, x = 2 * j + dj;
                float dv = fabsf(sP3[y * 64 + x] - v);
                sd2[y * 64 + x] = dv;
                d2g[y * 64 + x] = dv;
            }
    }
    __syncthreads();

    const int wave = tid >> 6, lane = tid & 63;

    // ---- stage B: specialized waves, no internal barriers ----
    if (wave == 0) {
        // pyr5 (16x16) + d3 (32x32): 4 outputs/lane
        float* d3g = dBase + d_off(3) + (size_t)p * 1024;
#pragma unroll
        for (int q = 0; q < 4; ++q) {
            int k = lane + 64 * q;
            int i = k >> 4, j = k & 15;
            float v = stencil6(sp4, 32, i, j);
            sp5[k] = v;
#pragma unroll
            for (int di = 0; di < 2; ++di)
#pragma unroll
                for (int dj = 0; dj < 2; ++dj) {
                    int y = 2 * i + di, x = 2 * j + dj;
                    float dv = fabsf(sp4[y * 32 + x] - v);
                    sd3[y * 32 + x] = dv;
                    d3g[y * 32 + x] = dv;
                }
        }
        // pyr6 (8x8) + d4 (16x16): 1 output/lane
        {
            int i = lane >> 3, j = lane & 7;
            float v = stencil6(sp5, 16, i, j);
            sp6[lane] = v;
            float* d4g = dBase + d_off(4) + (size_t)p * 256;
#pragma unroll
            for (int di = 0; di < 2; ++di)
#pragma unroll
                for (int dj = 0; dj < 2; ++dj) {
                    int y = 2 * i + di, x = 2 * j + dj;
                    float dv = fabsf(sp5[y * 16 + x] - v);
                    sd4[y * 16 + x] = dv;
                    d4g[y * 16 + x] = dv;
                }
        }
        // pyr7 (4x4) + d5 (8x8)
        if (lane < 16) {
            int i = lane >> 2, j = lane & 3;
            float v = stencil6(sp6, 8, i, j);
            sp7[lane] = v;
            float* d5g = dBase + d_off(5) + (size_t)p * 64;
#pragma unroll
            for (int di = 0; di < 2; ++di)
#pragma unroll
                for (int dj = 0; dj < 2; ++dj) {
                    int y = 2 * i + di, x = 2 * j + dj;
                    float dv = fabsf(sp6[y * 8 + x] - v);
                    sd5[y * 8 + x] = dv;
                    d5g[y * 8 + x] = dv;
                }
        }
        // pyr8 (2x2) + d6 (4x4)
        if (lane < 4) {
            int i = lane >> 1, j = lane & 1;
            float v = stencil6(sp7, 4, i, j);
            float* d6g = dBase + d_off(6) + (size_t)p * 16;
#pragma unroll
            for (int di = 0; di < 2; ++di)
#pragma unroll
                for (int dj = 0; dj < 2; ++dj) {
                    int y = 2 * i + di, x = 2 * j + dj;
                    float dv = fabsf(sp7[y * 4 + x] - v);
                    sd6[y * 4 + x] = dv;
                    d6g[y * 4 + x] = dv;
                }
        }
    } else if (wave == 1) {
        // li=1 stats: d1 in sP2 (128x128). Plane minmax + interior 7x7 tile maxima.
        const float4* sv = (const float4*)sP2;
        float mn = FINF, mx = -FINF;
        for (int k = lane; k < 4096; k += 64) {
            float4 v = sv[k];
            mn = fminf(mn, fminf(fminf(v.x, v.y), fminf(v.z, v.w)));
            mx = fmaxf(mx, fmaxf(fmaxf(v.x, v.y), fmaxf(v.z, v.w)));
        }
        wminmax64(mn, mx);
        float tmax = 0.f;
        if (lane < 49) {
            int tr = lane / 7, tc = lane % 7;
            const float4* base = (const float4*)(sP2 + (tr * 16) * 128 + tc * 16);
            float tm = -FINF;
            for (int r = 0; r < 16; ++r) {
#pragma unroll
                for (int c = 0; c < 4; ++c) {
                    float4 v = base[r * 32 + c];
                    tm = fmaxf(tm, fmaxf(fmaxf(v.x, v.y), fmaxf(v.z, v.w)));
                }
            }
            tmax = tm;
        }
        float sum = wsumx64(tmax);
        if (lane == 0) {
            float inv = 1.f / (mx - mn);
            float lm = (sum * (1.f / 49.f) - mn) * inv;
            float g = (1.f - lm) * (1.f - lm);
            A[1 * NPLANES + p] = g * inv;
            B[1 * NPLANES + p] = -mn * g * inv;
        }
    } else if (wave == 2) {
        // li=0 reduce from global tile stats (256 tiles, interior 15x15)
        float mn = FINF, mx = -FINF, su = 0.f;
#pragma unroll
        for (int q = 0; q < 4; ++q) {
            int t = lane + 64 * q;
            float tmn = tileMin[p * 256 + t];
            float tmx = tileMax[p * 256 + t];
            mn = fminf(mn, tmn);
            mx = fmaxf(mx, tmx);
            if ((t >> 4) < 15 && (t & 15) < 15) su += tmx;
        }
        wminmax64(mn, mx);
        float sum = wsumx64(su);
        if (lane == 0) {
            float inv = 1.f / (mx - mn);
            float lm = (sum * (1.f / 225.f) - mn) * inv;
            float g = (1.f - lm) * (1.f - lm);
            A[0 * NPLANES + p] = g * inv;
            B[0 * NPLANES + p] = -mn * g * inv;
        }
    }
    __syncthreads();

    // ---- stage C: one wave per level, shuffle-only stats ----
    if (wave == 0) {
        // li=2: sd2 (64x64). minmax + interior 3x3 tile maxima.
        const float4* sv = (const float4*)sd2;
        float mn = FINF, mx = -FINF;
#pragma unroll
        for (int q = 0; q < 16; ++q) {
            float4 v = sv[lane + 64 * q];
            mn = fminf(mn, fminf(fminf(v.x, v.y), fminf(v.z, v.w)));
            mx = fmaxf(mx, fmaxf(fmaxf(v.x, v.y), fmaxf(v.z, v.w)));
        }
        wminmax64(mn, mx);
        float tmax = -FINF;
        if (lane < 36) {
            int t = lane >> 2, r4 = lane & 3;       // tile t (0..8), row-group r4
            int tr = t / 3, tc = t % 3;
#pragma unroll
            for (int rr = 0; rr < 4; ++rr) {
                const float4* base = (const float4*)(sd2 + (16 * tr + 4 * r4 + rr) * 64 + 16 * tc);
#pragma unroll
                for (int c = 0; c < 4; ++c) {
                    float4 v = base[c];
                    tmax = fmaxf(tmax, fmaxf(fmaxf(v.x, v.y), fmaxf(v.z, v.w)));
                }
            }
        }
        tmax = fmaxf(tmax, __shfl_xor(tmax, 1, 64));
        tmax = fmaxf(tmax, __shfl_xor(tmax, 2, 64));
        float val = ((lane & 3) == 0 && lane < 36) ? tmax : 0.f;
        float s = wsumx64(val);
        if (lane == 0) {
            float inv = 1.f / (mx - mn);
            float lm = (s * (1.f / 9.f) - mn) * inv;
            float g = (1.f - lm) * (1.f - lm);
            A[2 * NPLANES + p] = g * inv;
            B[2 * NPLANES + p] = -mn * g * inv;
        }
    } else if (wave == 1) {
        // li=3: sd3 (32x32). minmax + single interior 16x16 tile max.
        const float4* sv = (const float4*)sd3;
        float mn = FINF, mx = -FINF;
#pragma unroll
        for (int q = 0; q < 4; ++q) {
            float4 v = sv[lane + 64 * q];
            mn = fminf(mn, fminf(fminf(v.x, v.y), fminf(v.z, v.w)));
            mx = fmaxf(mx, fmaxf(fmaxf(v.x, v.y), fmaxf(v.z, v.w)));
        }
        wminmax64(mn, mx);
        float4 e4 = sv[(lane >> 2) * 8 + (lane & 3)];  // rows 0-15, cols 0-15
        float e = fmaxf(fmaxf(e4.x, e4.y), fmaxf(e4.z, e4.w));
        float tn = e, tm = e;
        wminmax64(tn, tm);
        if (lane == 0) {
            float inv = 1.f / (mx - mn);
            float lm = (tm - mn) * inv;
            float g = (1.f - lm) * (1.f - lm);
            A[3 * NPLANES + p] = g * inv;
            B[3 * NPLANES + p] = -mn * g * inv;
        }
    } else if (wave == 2) {
        // li=4: sd4 (16x16), lm=0
        float4 v = ((const float4*)sd4)[lane];
        float mn = fminf(fminf(v.x, v.y), fminf(v.z, v.w));
        float mx = fmaxf(fmaxf(v.x, v.y), fmaxf(v.z, v.w));
        wminmax64(mn, mx);
        if (lane == 0) {
            float inv = 1.f / (mx - mn);
            A[4 * NPLANES + p] = inv; B[4 * NPLANES + p] = -mn * inv;
        }
    } else if (wave == 3) {
        // li=5: sd5 (8x8), lm=0
        float v = sd5[lane];
        float mn = v, mx = v;
        wminmax64(mn, mx);
        if (lane == 0) {
            float inv = 1.f / (mx - mn);
            A[5 * NPLANES + p] = inv; B[5 * NPLANES + p] = -mn * inv;
        }
    } else if (wave == 4) {
        // li=6: sd6 (4x4), lm=0
        float v = (lane < 16) ? sd6[lane] : sd6[0];
        float mn = v, mx = v;
        wminmax64(mn, mx);
        if (lane == 0) {
            float inv = 1.f / (mx - mn);
            A[6 * NPLANES + p] = inv; B[6 * NPLANES + p] = -mn * inv;
        }
    }
}

// Tiled final gather, register-patch bilerp (R6-verified).
__global__ __launch_bounds__(256) void final_kernel(const float* __restrict__ dBase,
                                                    const float* __restrict__ A,
                                                    const float* __restrict__ Bc,
                                                    float* __restrict__ out) {
    __shared__ float patch[1700];
    __shared__ float sBtot;
    const int tid = threadIdx.x;
    const int b = blockIdx.x >> 6;
    const int tile = blockIdx.x & 63;
    const int yb = (tile >> 3) << 6;
    const int xb = (tile & 7) << 6;

    if (tid == 0) {
        float s = 0.f;
        for (int k = 0; k < 7; ++k)
            for (int c = 0; c < 3; ++c) s += Bc[k * NPLANES + b * 3 + c];
        sBtot = s;
    }

    const int dims[7] = {34, 18, 10, 6, 4, 3, 3};
    const int lofs[7] = {0, 1156, 1480, 1580, 1616, 1632, 1641};
    int baseY[7], baseX[7];
#pragma unroll
    for (int li = 0; li < 7; ++li) {
        const int S = 256 >> li;
        const float s = 1.f / (float)(2 << li);
        baseY[li] = (int)floorf((yb + 0.5f) * s - 0.5f);
        baseX[li] = (int)floorf((xb + 0.5f) * s - 0.5f);
        const int dim = dims[li];
        const int n = dim * dim;
        const float* d0p = dBase + d_off(li) + (size_t)(b * 3) * S * S;
        const float* d1p = d0p + S * S;
        const float* d2p = d1p + S * S;
        const float A0 = A[li * NPLANES + b * 3 + 0];
        const float A1 = A[li * NPLANES + b * 3 + 1];
        const float A2 = A[li * NPLANES + b * 3 + 2];
        for (int k = tid; k < n; k += 256) {
            int r = k / dim, c = k - r * dim;
            int sr = min(max(baseY[li] + r, 0), S - 1);
            int sc = min(max(baseX[li] + c, 0), S - 1);
            int si = sr * S + sc;
            patch[lofs[li] + k] = A0 * d0p[si] + A1 * d1p[si] + A2 * d2p[si];
        }
    }
    __syncthreads();

    const int ty = tid >> 4, tx = tid & 15;
    const int gy0 = yb + (ty << 2), gx0 = xb + (tx << 2);
    float acc[4][4];
#pragma unroll
    for (int i = 0; i < 4; ++i)
#pragma unroll
        for (int j = 0; j < 4; ++j) acc[i][j] = 0.f;

    // ---- level 0 (scale 1/2): 4x4 register patch ----
    {
        const int dim = 34;
        float wy[4], wx[4];
        int ry[4], cx[4];
#pragma unroll
        for (int k = 0; k < 4; ++k) {
            float fy = (gy0 + k + 0.5f) * 0.5f - 0.5f;
            float fl = floorf(fy);
            wy[k] = fy - fl; ry[k] = (int)fl - baseY[0];
            float fx = (gx0 + k + 0.5f) * 0.5f - 0.5f;
            fl = floorf(fx);
            wx[k] = fx - fl; cx[k] = (int)fl - baseX[0];
        }
        const int r0 = ry[0], c0 = cx[0];
        const float* pp = patch + r0 * dim + c0;
        float P[4][4];
#pragma unroll
        for (int r = 0; r < 4; ++r)
#pragma unroll
            for (int c = 0; c < 4; ++c) P[r][c] = pp[r * dim + c];
        float h[4][4];
#pragma unroll
        for (int j = 0; j < 4; ++j) {
            int dx = cx[j] - c0;
#pragma unroll
            for (int r = 0; r < 4; ++r) {
                float a = dx == 0 ? P[r][0] : (dx == 1 ? P[r][1] : P[r][2]);
                float bb = dx == 0 ? P[r][1] : (dx == 1 ? P[r][2] : P[r][3]);
                h[r][j] = a + wx[j] * (bb - a);
            }
        }
#pragma unroll
        for (int i = 0; i < 4; ++i) {
            int dy = ry[i] - r0;
#pragma unroll
            for (int j = 0; j < 4; ++j) {
                float h0 = dy == 0 ? h[0][j] : (dy == 1 ? h[1][j] : h[2][j]);
                float h1 = dy == 0 ? h[1][j] : (dy == 1 ? h[2][j] : h[3][j]);
                acc[i][j] += h0 + wy[i] * (h1 - h0);
            }
        }
    }
    // ---- levels 1..6 (scale <= 1/4): 3x3 register patch ----
#pragma unroll
    for (int li = 1; li < 7; ++li) {
        const int dim = dims[li];
        const float* P0 = patch + lofs[li];
        const float s = 1.f / (float)(2 << li);
        float wy[4], wx[4];
        int ry[4], cx[4];
#pragma unroll
        for (int k = 0; k < 4; ++k) {
            float fy = (gy0 + k + 0.5f) * s - 0.5f;
            float fl = floorf(fy);
            wy[k] = fy - fl; ry[k] = (int)fl - baseY[li];
            float fx = (gx0 + k + 0.5f) * s - 0.5f;
            fl = floorf(fx);
            wx[k] = fx - fl; cx[k] = (int)fl - baseX[li];
        }
        const int r0 = ry[0], c0 = cx[0];
        const float* pp = P0 + r0 * dim + c0;
        float P[3][3];
#pragma unroll
        for (int r = 0; r < 3; ++r)
#pragma unroll
            for (int c = 0; c < 3; ++c) P[r][c] = pp[r * dim + c];
        float h[3][4];
#pragma unroll
        for (int j = 0; j < 4; ++j) {
            int dx = cx[j] - c0;   // 0 or 1
#pragma unroll
            for (int r = 0; r < 3; ++r) {
                float a = dx == 0 ? P[r][0] : P[r][1];
                float bb = dx == 0 ? P[r][1] : P[r][2];
                h[r][j] = a + wx[j] * (bb - a);
            }
        }
#pragma unroll
        for (int i = 0; i < 4; ++i) {
            int dy = ry[i] - r0;   // 0 or 1
#pragma unroll
            for (int j = 0; j < 4; ++j) {
                float h0 = dy == 0 ? h[0][j] : h[1][j];
                float h1 = dy == 0 ? h[1][j] : h[2][j];
                acc[i][j] += h0 + wy[i] * (h1 - h0);
            }
        }
    }

    const float bt = sBtot;
    float* op = out + ((size_t)b * 512 + gy0) * 512 + gx0;
#pragma unroll
    for (int i = 0; i < 4; ++i) {
        float4 v;
        v.x = (acc[i][0] + bt) * (1.f / 3.f);
        v.y = (acc[i][1] + bt) * (1.f / 3.f);
        v.z = (acc[i][2] + bt) * (1.f / 3.f);
        v.w = (acc[i][3] + bt) * (1.f / 3.f);
        *(float4*)(op + (size_t)i * 512) = v;
    }
}

extern "C" void kernel_launch(void* const* d_in, const int* in_sizes, int n_in,
                              void* d_out, int out_size, void* d_ws, size_t ws_size,
                              hipStream_t stream) {
    (void)in_sizes; (void)n_in; (void)out_size; (void)ws_size;
    const float* x = (const float*)d_in[0];
    float* ws = (float*)d_ws;
    float* out = (float*)d_out;

    // Workspace layout (float offsets):
    float* pyr1 = ws;                  // 256^2*24 = 1572864
    float* pyr2 = ws + 1572864;        // 128^2*24 =  393216
    float* dBase = ws + 1966080;       // d0..d6   = 2097024
    float* tileMin = ws + 4063104;     // 6144 (li=0 only)
    float* tileMax = ws + 4069248;     // 6144
    float* A = ws + 4075392;           // 168
    float* Bc = ws + 4075560;          // 168

    // Level 1 from raw x (initial _norm_pc is an affine no-op for the output)
    pyrdown_tiled<512, false><<<NPLANES * 64, 256, 0, stream>>>(x, pyr1, nullptr, nullptr, nullptr);
    pyrdown_tiled<256, true><<<NPLANES * 16, 256, 0, stream>>>(pyr1, pyr2, dBase + d_off(0), tileMin, tileMax);
    fused_small_kernel<<<NPLANES, 1024, 0, stream>>>(pyr2, dBase, tileMin, tileMax, A, Bc);
    final_kernel<<<8 * 64, 256, 0, stream>>>(dBase, A, Bc, out);
}

// Round 9
// 103.941 us; speedup vs baseline: 1.2850x; 1.0527x over previous
//
#include <hip/hip_runtime.h>
#include <math.h>

#define NPLANES 24   // B*C = 8*3
#define FINF 3.402823466e38f

__host__ __device__ __forceinline__ int d_off(int li) {
    // cumulative float offset of d-level li inside dBase (sizes 256^2..4^2 x24)
    return 2097152 - (2097152 >> (2 * li));
}

__device__ __forceinline__ int refl(int v, int S) {
    if (v < 0) v = -v;
    if (v >= S) v = 2 * S - 2 - v;
    return v;
}

// ---- shuffle reductions (no LDS, no barriers) ----
__device__ __forceinline__ void wminmax64(float& mn, float& mx) {
#pragma unroll
    for (int o = 32; o > 0; o >>= 1) {
        mn = fminf(mn, __shfl_xor(mn, o, 64));
        mx = fmaxf(mx, __shfl_xor(mx, o, 64));
    }
}
__device__ __forceinline__ float wsumx64(float v) {
#pragma unroll
    for (int o = 32; o > 0; o >>= 1) v += __shfl_xor(v, o, 64);
    return v;
}
__device__ __forceinline__ void wminmax16(float& mn, float& mx) {
#pragma unroll
    for (int o = 8; o > 0; o >>= 1) {
        mn = fminf(mn, __shfl_xor(mn, o, 16));
        mx = fmaxf(mx, __shfl_xor(mx, o, 16));
    }
}

// 6-tap separable collapsed pyrdown stencil on an LDS plane of size SxS.
__device__ __forceinline__ float stencil6(const float* s, int S, int i, int j) {
    const float w[6] = {1.f, 5.f, 10.f, 10.f, 5.f, 1.f};
    int rx[6];
#pragma unroll
    for (int b = 0; b < 6; ++b) rx[b] = refl(2 * j - 2 + b, S);
    float acc = 0.f;
#pragma unroll
    for (int a = 0; a < 6; ++a) {
        int ry = refl(2 * i - 2 + a, S);
        const float* rp = s + ry * S;
        float r = 0.f;
#pragma unroll
        for (int b = 0; b < 6; ++b) r += w[b] * rp[rx[b]];
        acc += w[a] * r;
    }
    return acc * (1.f / 1024.f);
}

// L1 pyrdown: x (512^2) -> pyr1 (256^2). Block = 32x32 output tile.
__global__ __launch_bounds__(256) void pyrdown_l1(const float* __restrict__ in,
                                                  float* __restrict__ out) {
    constexpr int IS = 512, SO = 256, TO = 32, TI = 68, TPA = 8;
    __shared__ float sIn[TI * TI];
    __shared__ float sH[TI * TO];
    const int tid = threadIdx.x;
    const int p = blockIdx.x / (TPA * TPA);
    const int t = blockIdx.x % (TPA * TPA);
    const int ty = t / TPA, tx = t % TPA;
    const int oy = ty * TO, ox = tx * TO;
    const int iy = 2 * oy - 2, ix = 2 * ox - 2;
    const float* ip = in + (size_t)p * IS * IS;

    for (int k = tid; k < TI * TI; k += 256) {
        int r = k / TI, c = k - r * TI;
        sIn[k] = ip[refl(iy + r, IS) * IS + refl(ix + c, IS)];
    }
    __syncthreads();
    for (int k = tid; k < TI * 8; k += 256) {
        int r = k >> 3, jq = k & 7;
        const float4* rp = (const float4*)(sIn + r * TI + 8 * jq);
        float4 v0 = rp[0], v1 = rp[1], v2 = rp[2];
        float4 o;
        o.x = v0.x + 5.f * v0.y + 10.f * v0.z + 10.f * v0.w + 5.f * v1.x + v1.y;
        o.y = v0.z + 5.f * v0.w + 10.f * v1.x + 10.f * v1.y + 5.f * v1.z + v1.w;
        o.z = v1.x + 5.f * v1.y + 10.f * v1.z + 10.f * v1.w + 5.f * v2.x + v2.y;
        o.w = v1.z + 5.f * v1.w + 10.f * v2.x + 10.f * v2.y + 5.f * v2.z + v2.w;
        *(float4*)(sH + r * TO + 4 * jq) = o;
    }
    __syncthreads();
    {
        int i = tid >> 3, jq = tid & 7;
        const float* base = sH + (2 * i) * TO + 4 * jq;
        float4 r0 = *(const float4*)(base);
        float4 r1 = *(const float4*)(base + TO);
        float4 r2 = *(const float4*)(base + 2 * TO);
        float4 r3 = *(const float4*)(base + 3 * TO);
        float4 r4 = *(const float4*)(base + 4 * TO);
        float4 r5 = *(const float4*)(base + 5 * TO);
        float4 o;
        o.x = (r0.x + 5.f * r1.x + 10.f * r2.x + 10.f * r3.x + 5.f * r4.x + r5.x) * (1.f / 1024.f);
        o.y = (r0.y + 5.f * r1.y + 10.f * r2.y + 10.f * r3.y + 5.f * r4.y + r5.y) * (1.f / 1024.f);
        o.z = (r0.z + 5.f * r1.z + 10.f * r2.z + 10.f * r3.z + 5.f * r4.z + r5.z) * (1.f / 1024.f);
        o.w = (r0.w + 5.f * r1.w + 10.f * r2.w + 10.f * r3.w + 5.f * r4.w + r5.w) * (1.f / 1024.f);
        *(float4*)(out + (size_t)p * SO * SO + (size_t)(oy + i) * SO + ox + 4 * jq) = o;
    }
}

// Fused L2+L3 pyrdown: pyr1 -> {pyr3 tile, d0 region, d1 region, li=0/li=1
// tile stats}. pyr2 lives only in LDS (36x36 patch incl. halo). Block = one
// 16x16 pyr3 tile; grid = 24 planes x 16 tiles = 384 blocks.
__global__ __launch_bounds__(256) void pyrdown23(const float* __restrict__ pyr1,
                                                 float* __restrict__ pyr3,
                                                 float* __restrict__ dBase,
                                                 float* __restrict__ tmin0,
                                                 float* __restrict__ tmax0,
                                                 float* __restrict__ tmin1,
                                                 float* __restrict__ tmax1) {
    __shared__ float sIn[5776];   // 76x76 pyr1 patch (reflect-staged)
    __shared__ float sH1[2736];   // 76x36
    __shared__ float sP2[1296];   // 36x36 pyr2 patch, global rows py0..py0+35
    __shared__ float sH2[576];    // 36x16
    __shared__ float sP3t[256];   // 16x16
    const int tid = threadIdx.x;
    const int p = blockIdx.x >> 4;
    const int t = blockIdx.x & 15;
    const int t3y = t >> 2, t3x = t & 3;
    const int oy3 = t3y * 16, ox3 = t3x * 16;   // pyr3 tile origin (S=64)
    const int oy2 = 2 * oy3, ox2 = 2 * ox3;     // pyr2 tile origin (S=128)
    const int py0 = oy2 - 2, px0 = ox2 - 2;     // pyr2 patch origin
    const int iy0 = 2 * py0 - 2, ix0 = 2 * px0 - 2;  // pyr1 patch origin
    const float* ip = pyr1 + (size_t)p * 65536;

    for (int k = tid; k < 5776; k += 256) {
        int r = k / 76, c = k - r * 76;
        sIn[k] = ip[refl(iy0 + r, 256) * 256 + refl(ix0 + c, 256)];
    }
    __syncthreads();
    // h1: 76 rows x 36 pyr2-cols (all indices interior to the staged patch)
    for (int k = tid; k < 2736; k += 256) {
        int r = k / 36, c2 = k - r * 36;
        const float* rp = sIn + r * 76 + 2 * c2;
        sH1[k] = rp[0] + 5.f * rp[1] + 10.f * rp[2] + 10.f * rp[3] + 5.f * rp[4] + rp[5];
    }
    __syncthreads();
    // v1 -> sP2 (36x36). Halo rows/cols at plane edges are unused (reflection
    // redirects pyr3/d1 reads into the interior).
    for (int k = tid; k < 1296; k += 256) {
        int r2 = k / 36, c2 = k - r2 * 36;
        const float* cp = sH1 + 2 * r2 * 36 + c2;
        sP2[k] = (cp[0] + 5.f * cp[36] + 10.f * cp[72] + 10.f * cp[108] +
                  5.f * cp[144] + cp[180]) * (1.f / 1024.f);
    }
    __syncthreads();
    // h2: 36 rows x 16 pyr3-cols, reflect pyr2 col index at S=128
    for (int k = tid; k < 576; k += 256) {
        int r2 = k >> 4, c3 = k & 15;
        int gb = 2 * (ox3 + c3) - 2;
        const float* rp = sP2 + r2 * 36;
        sH2[k] = rp[refl(gb, 128) - px0] + 5.f * rp[refl(gb + 1, 128) - px0] +
                 10.f * rp[refl(gb + 2, 128) - px0] + 10.f * rp[refl(gb + 3, 128) - px0] +
                 5.f * rp[refl(gb + 4, 128) - px0] + rp[refl(gb + 5, 128) - px0];
    }
    __syncthreads();
    // v2 -> sP3t + global pyr3
    {
        int i3 = tid >> 4, c3 = tid & 15;
        int gb = 2 * (oy3 + i3) - 2;
        float s = sH2[(refl(gb, 128) - py0) * 16 + c3] +
                  5.f * sH2[(refl(gb + 1, 128) - py0) * 16 + c3] +
                  10.f * sH2[(refl(gb + 2, 128) - py0) * 16 + c3] +
                  10.f * sH2[(refl(gb + 3, 128) - py0) * 16 + c3] +
                  5.f * sH2[(refl(gb + 4, 128) - py0) * 16 + c3] +
                  sH2[(refl(gb + 5, 128) - py0) * 16 + c3];
        float v = s * (1.f / 1024.f);
        sP3t[tid] = v;
        pyr3[(size_t)p * 4096 + (size_t)(oy3 + i3) * 64 + ox3 + c3] = v;
    }
    __syncthreads();
    // d0 = |pyr1 - up(pyr2)| over the 64x64 region; per-thread 4x4 block,
    // stats tile (16x16) = 16 threads -> shuffle-16 reduce.
    {
        float* d0g = dBase + (size_t)p * 65536;
        int ti = tid >> 4, si = tid & 15;
        int tr = ti >> 2, tc = ti & 3;
        int y0 = tr * 16 + (si >> 2) * 4, x0 = tc * 16 + (si & 3) * 4;
        float mn = FINF, mx = -FINF;
#pragma unroll
        for (int r = 0; r < 4; ++r) {
            int y = y0 + r;
            const float* srow = sIn + (y + 6) * 76 + x0 + 6;
            const float* prow = sP2 + ((y >> 1) + 2) * 36 + 2 + (x0 >> 1);
            float e0 = prow[0], e1 = prow[1];
            float4 dv;
            dv.x = fabsf(srow[0] - e0);
            dv.y = fabsf(srow[1] - e0);
            dv.z = fabsf(srow[2] - e1);
            dv.w = fabsf(srow[3] - e1);
            *(float4*)(d0g + (size_t)(4 * oy3 + y) * 256 + 4 * ox3 + x0) = dv;
            mn = fminf(mn, fminf(fminf(dv.x, dv.y), fminf(dv.z, dv.w)));
            mx = fmaxf(mx, fmaxf(fmaxf(dv.x, dv.y), fmaxf(dv.z, dv.w)));
        }
        wminmax16(mn, mx);
        if (si == 0) {
            int g0 = p * 256 + (t3y * 4 + tr) * 16 + (t3x * 4 + tc);
            tmin0[g0] = mn;
            tmax0[g0] = mx;
        }
    }
    // d1 = |pyr2 - up(pyr3)| over the 32x32 region; wave 0 only (4 tiles x 16).
    if (tid < 64) {
        float* d1g = dBase + d_off(1) + (size_t)p * 16384;
        int ti = tid >> 4, si = tid & 15;
        int tr = ti >> 1, tc = ti & 1;
        int y0 = tr * 16 + (si >> 2) * 4, x0 = tc * 16 + (si & 3) * 4;
        float mn = FINF, mx = -FINF;
#pragma unroll
        for (int r = 0; r < 4; ++r) {
            int y = y0 + r;
            const float* prow = sP2 + (y + 2) * 36 + 2 + x0;
            const float* qrow = sP3t + (y >> 1) * 16 + (x0 >> 1);
            float e0 = qrow[0], e1 = qrow[1];
            float4 dv;
            dv.x = fabsf(prow[0] - e0);
            dv.y = fabsf(prow[1] - e0);
            dv.z = fabsf(prow[2] - e1);
            dv.w = fabsf(prow[3] - e1);
            *(float4*)(d1g + (size_t)(oy2 + y) * 128 + ox2 + x0) = dv;
            mn = fminf(mn, fminf(fminf(dv.x, dv.y), fminf(dv.z, dv.w)));
            mx = fmaxf(mx, fmaxf(fmaxf(dv.x, dv.y), fmaxf(dv.z, dv.w)));
        }
        wminmax16(mn, mx);
        if (si == 0) {
            int g1 = p * 64 + (t3y * 2 + tr) * 8 + (t3x * 2 + tc);
            tmin1[g1] = mn;
            tmax1[g1] = mx;
        }
    }
}

// One block (1024 threads) per plane, barrier-light: load pyr3 (16 KB) ->
// pyr4+d2 (all threads) -> wave-specialized chain + stats.
__global__ __launch_bounds__(1024) void fused_small_kernel(const float* __restrict__ pyr3,
                                                           float* __restrict__ dBase,
                                                           const float* __restrict__ tmin0,
                                                           const float* __restrict__ tmax0,
                                                           const float* __restrict__ tmin1,
                                                           const float* __restrict__ tmax1,
                                                           float* __restrict__ A,
                                                           float* __restrict__ B) {
    __shared__ float sP3[4096];
    __shared__ float sd2[4096];
    __shared__ float sp4[1024], sd3[1024];
    __shared__ float sp5[256], sd4[256];
    __shared__ float sp6[64], sd5[64];
    __shared__ float sp7[16], sd6[16];
    const int tid = threadIdx.x;
    const int p = blockIdx.x;

    if (tid < 1024) ((float4*)sP3)[tid] = ((const float4*)(pyr3 + (size_t)p * 4096))[tid];
    __syncthreads();
    // stage A: pyr4 (32x32) + d2 (64x64), one pyr4 output per thread
    {
        float* d2g = dBase + d_off(2) + (size_t)p * 4096;
        int i = tid >> 5, j = tid & 31;
        float v = stencil6(sP3, 64, i, j);
        sp4[tid] = v;
#pragma unroll
        for (int di = 0; di < 2; ++di)
#pragma unroll
            for (int dj = 0; dj < 2; ++dj) {
                int y = 2 * i + di, x = 2 * j + dj;
                float dv = fabsf(sP3[y * 64 + x] - v);
                sd2[y * 64 + x] = dv;
                d2g[y * 64 + x] = dv;
            }
    }
    __syncthreads();

    const int wave = tid >> 6, lane = tid & 63;

    // ---- stage B: specialized waves, no internal barriers ----
    if (wave == 0) {
        // pyr5 (16x16) + d3 (32x32): 4 outputs/lane
        float* d3g = dBase + d_off(3) + (size_t)p * 1024;
#pragma unroll
        for (int q = 0; q < 4; ++q) {
            int k = lane + 64 * q;
            int i = k >> 4, j = k & 15;
            float v = stencil6(sp4, 32, i, j);
            sp5[k] = v;
#pragma unroll
            for (int di = 0; di < 2; ++di)
#pragma unroll
                for (int dj = 0; dj < 2; ++dj) {
                    int y = 2 * i + di, x = 2 * j + dj;
                    float dv = fabsf(sp4[y * 32 + x] - v);
                    sd3[y * 32 + x] = dv;
                    d3g[y * 32 + x] = dv;
                }
        }
        // pyr6 (8x8) + d4 (16x16)
        {
            int i = lane >> 3, j = lane & 7;
            float v = stencil6(sp5, 16, i, j);
            sp6[lane] = v;
            float* d4g = dBase + d_off(4) + (size_t)p * 256;
#pragma unroll
            for (int di = 0; di < 2; ++di)
#pragma unroll
                for (int dj = 0; dj < 2; ++dj) {
                    int y = 2 * i + di, x = 2 * j + dj;
                    float dv = fabsf(sp5[y * 16 + x] - v);
                    sd4[y * 16 + x] = dv;
                    d4g[y * 16 + x] = dv;
                }
        }
        // pyr7 (4x4) + d5 (8x8)
        if (lane < 16) {
            int i = lane >> 2, j = lane & 3;
            float v = stencil6(sp6, 8, i, j);
            sp7[lane] = v;
            float* d5g = dBase + d_off(5) + (size_t)p * 64;
#pragma unroll
            for (int di = 0; di < 2; ++di)
#pragma unroll
                for (int dj = 0; dj < 2; ++dj) {
                    int y = 2 * i + di, x = 2 * j + dj;
                    float dv = fabsf(sp6[y * 8 + x] - v);
                    sd5[y * 8 + x] = dv;
                    d5g[y * 8 + x] = dv;
                }
        }
        // pyr8 (2x2) + d6 (4x4)
        if (lane < 4) {
            int i = lane >> 1, j = lane & 1;
            float v = stencil6(sp7, 4, i, j);
            float* d6g = dBase + d_off(6) + (size_t)p * 16;
#pragma unroll
            for (int di = 0; di < 2; ++di)
#pragma unroll
                for (int dj = 0; dj < 2; ++dj) {
                    int y = 2 * i + di, x = 2 * j + dj;
                    float dv = fabsf(sp7[y * 4 + x] - v);
                    sd6[y * 4 + x] = dv;
                    d6g[y * 4 + x] = dv;
                }
        }
    } else if (wave == 1) {
        // li=1 reduce from tile stats (64 tiles, interior 7x7)
        float tmn = tmin1[p * 64 + lane];
        float tmx = tmax1[p * 64 + lane];
        float mn = tmn, mx = tmx;
        wminmax64(mn, mx);
        float su = ((lane >> 3) < 7 && (lane & 7) < 7) ? tmx : 0.f;
        float sum = wsumx64(su);
        if (lane == 0) {
            float inv = 1.f / (mx - mn);
            float lm = (sum * (1.f / 49.f) - mn) * inv;
            float g = (1.f - lm) * (1.f - lm);
            A[1 * NPLANES + p] = g * inv;
            B[1 * NPLANES + p] = -mn * g * inv;
        }
    } else if (wave == 2) {
        // li=0 reduce from tile stats (256 tiles, interior 15x15)
        float mn = FINF, mx = -FINF, su = 0.f;
#pragma unroll
        for (int q = 0; q < 4; ++q) {
            int t = lane + 64 * q;
            float tmn = tmin0[p * 256 + t];
            float tmx = tmax0[p * 256 + t];
            mn = fminf(mn, tmn);
            mx = fmaxf(mx, tmx);
            if ((t >> 4) < 15 && (t & 15) < 15) su += tmx;
        }
        wminmax64(mn, mx);
        float sum = wsumx64(su);
        if (lane == 0) {
            float inv = 1.f / (mx - mn);
            float lm = (sum * (1.f / 225.f) - mn) * inv;
            float g = (1.f - lm) * (1.f - lm);
            A[0 * NPLANES + p] = g * inv;
            B[0 * NPLANES + p] = -mn * g * inv;
        }
    }
    __syncthreads();

    // ---- stage C: one wave per level, shuffle-only stats ----
    if (wave == 0) {
        // li=2: sd2 (64x64), interior 3x3 tiles
        const float4* sv = (const float4*)sd2;
        float mn = FINF, mx = -FINF;
#pragma unroll
        for (int q = 0; q < 16; ++q) {
            float4 v = sv[lane + 64 * q];
            mn = fminf(mn, fminf(fminf(v.x, v.y), fminf(v.z, v.w)));
            mx = fmaxf(mx, fmaxf(fmaxf(v.x, v.y), fmaxf(v.z, v.w)));
        }
        wminmax64(mn, mx);
        float tmax = -FINF;
        if (lane < 36) {
            int t = lane >> 2, r4 = lane & 3;
            int tr = t / 3, tc = t % 3;
#pragma unroll
            for (int rr = 0; rr < 4; ++rr) {
                const float4* base = (const float4*)(sd2 + (16 * tr + 4 * r4 + rr) * 64 + 16 * tc);
#pragma unroll
                for (int c = 0; c < 4; ++c) {
                    float4 v = base[c];
                    tmax = fmaxf(tmax, fmaxf(fmaxf(v.x, v.y), fmaxf(v.z, v.w)));
                }
            }
        }
        tmax = fmaxf(tmax, __shfl_xor(tmax, 1, 64));
        tmax = fmaxf(tmax, __shfl_xor(tmax, 2, 64));
        float val = ((lane & 3) == 0 && lane < 36) ? tmax : 0.f;
        float s = wsumx64(val);
        if (lane == 0) {
            float inv = 1.f / (mx - mn);
            float lm = (s * (1.f / 9.f) - mn) * inv;
            float g = (1.f - lm) * (1.f - lm);
            A[2 * NPLANES + p] = g * inv;
            B[2 * NPLANES + p] = -mn * g * inv;
        }
    } else if (wave == 1) {
        // li=3: sd3 (32x32), single interior 16x16 tile
        const float4* sv = (const float4*)sd3;
        float mn = FINF, mx = -FINF;
#pragma unroll
        for (int q = 0; q < 4; ++q) {
            float4 v = sv[lane + 64 * q];
            mn = fminf(mn, fminf(fminf(v.x, v.y), fminf(v.z, v.w)));
            mx = fmaxf(mx, fmaxf(fmaxf(v.x, v.y), fmaxf(v.z, v.w)));
        }
        wminmax64(mn, mx);
        float4 e4 = sv[(lane >> 2) * 8 + (lane & 3)];
        float e = fmaxf(fmaxf(e4.x, e4.y), fmaxf(e4.z, e4.w));
        float tn = e, tm = e;
        wminmax64(tn, tm);
        if (lane == 0) {
            float inv = 1.f / (mx - mn);
            float lm = (tm - mn) * inv;
            float g = (1.f - lm) * (1.f - lm);
            A[3 * NPLANES + p] = g * inv;
            B[3 * NPLANES + p] = -mn * g * inv;
        }
    } else if (wave == 2) {
        float4 v = ((const float4*)sd4)[lane];
        float mn = fminf(fminf(v.x, v.y), fminf(v.z, v.w));
        float mx = fmaxf(fmaxf(v.x, v.y), fmaxf(v.z, v.w));
        wminmax64(mn, mx);
        if (lane == 0) {
            float inv = 1.f / (mx - mn);
            A[4 * NPLANES + p] = inv; B[4 * NPLANES + p] = -mn * inv;
        }
    } else if (wave == 3) {
        float v = sd5[lane];
        float mn = v, mx = v;
        wminmax64(mn, mx);
        if (lane == 0) {
            float inv = 1.f / (mx - mn);
            A[5 * NPLANES + p] = inv; B[5 * NPLANES + p] = -mn * inv;
        }
    } else if (wave == 4) {
        float v = (lane < 16) ? sd6[lane] : sd6[0];
        float mn = v, mx = v;
        wminmax64(mn, mx);
        if (lane == 0) {
            float inv = 1.f / (mx - mn);
            A[6 * NPLANES + p] = inv; B[6 * NPLANES + p] = -mn * inv;
        }
    }
}

// Tiled final gather, register-patch bilerp (R6-verified).
__global__ __launch_bounds__(256) void final_kernel(const float* __restrict__ dBase,
                                                    const float* __restrict__ A,
                                                    const float* __restrict__ Bc,
                                                    float* __restrict__ out) {
    __shared__ float patch[1700];
    __shared__ float sBtot;
    const int tid = threadIdx.x;
    const int b = blockIdx.x >> 6;
    const int tile = blockIdx.x & 63;
    const int yb = (tile >> 3) << 6;
    const int xb = (tile & 7) << 6;

    if (tid == 0) {
        float s = 0.f;
        for (int k = 0; k < 7; ++k)
            for (int c = 0; c < 3; ++c) s += Bc[k * NPLANES + b * 3 + c];
        sBtot = s;
    }

    const int dims[7] = {34, 18, 10, 6, 4, 3, 3};
    const int lofs[7] = {0, 1156, 1480, 1580, 1616, 1632, 1641};
    int baseY[7], baseX[7];
#pragma unroll
    for (int li = 0; li < 7; ++li) {
        const int S = 256 >> li;
        const float s = 1.f / (float)(2 << li);
        baseY[li] = (int)floorf((yb + 0.5f) * s - 0.5f);
        baseX[li] = (int)floorf((xb + 0.5f) * s - 0.5f);
        const int dim = dims[li];
        const int n = dim * dim;
        const float* d0p = dBase + d_off(li) + (size_t)(b * 3) * S * S;
        const float* d1p = d0p + S * S;
        const float* d2p = d1p + S * S;
        const float A0 = A[li * NPLANES + b * 3 + 0];
        const float A1 = A[li * NPLANES + b * 3 + 1];
        const float A2 = A[li * NPLANES + b * 3 + 2];
        for (int k = tid; k < n; k += 256) {
            int r = k / dim, c = k - r * dim;
            int sr = min(max(baseY[li] + r, 0), S - 1);
            int sc = min(max(baseX[li] + c, 0), S - 1);
            int si = sr * S + sc;
            patch[lofs[li] + k] = A0 * d0p[si] + A1 * d1p[si] + A2 * d2p[si];
        }
    }
    __syncthreads();

    const int ty = tid >> 4, tx = tid & 15;
    const int gy0 = yb + (ty << 2), gx0 = xb + (tx << 2);
    float acc[4][4];
#pragma unroll
    for (int i = 0; i < 4; ++i)
#pragma unroll
        for (int j = 0; j < 4; ++j) acc[i][j] = 0.f;

    // ---- level 0 (scale 1/2): 4x4 register patch ----
    {
        const int dim = 34;
        float wy[4], wx[4];
        int ry[4], cx[4];
#pragma unroll
        for (int k = 0; k < 4; ++k) {
            float fy = (gy0 + k + 0.5f) * 0.5f - 0.5f;
            float fl = floorf(fy);
            wy[k] = fy - fl; ry[k] = (int)fl - baseY[0];
            float fx = (gx0 + k + 0.5f) * 0.5f - 0.5f;
            fl = floorf(fx);
            wx[k] = fx - fl; cx[k] = (int)fl - baseX[0];
        }
        const int r0 = ry[0], c0 = cx[0];
        const float* pp = patch + r0 * dim + c0;
        float P[4][4];
#pragma unroll
        for (int r = 0; r < 4; ++r)
#pragma unroll
            for (int c = 0; c < 4; ++c) P[r][c] = pp[r * dim + c];
        float h[4][4];
#pragma unroll
        for (int j = 0; j < 4; ++j) {
            int dx = cx[j] - c0;
#pragma unroll
            for (int r = 0; r < 4; ++r) {
                float a = dx == 0 ? P[r][0] : (dx == 1 ? P[r][1] : P[r][2]);
                float bb = dx == 0 ? P[r][1] : (dx == 1 ? P[r][2] : P[r][3]);
                h[r][j] = a + wx[j] * (bb - a);
            }
        }
#pragma unroll
        for (int i = 0; i < 4; ++i) {
            int dy = ry[i] - r0;
#pragma unroll
            for (int j = 0; j < 4; ++j) {
                float h0 = dy == 0 ? h[0][j] : (dy == 1 ? h[1][j] : h[2][j]);
                float h1 = dy == 0 ? h[1][j] : (dy == 1 ? h[2][j] : h[3][j]);
                acc[i][j] += h0 + wy[i] * (h1 - h0);
            }
        }
    }
    // ---- levels 1..6 (scale <= 1/4): 3x3 register patch ----
#pragma unroll
    for (int li = 1; li < 7; ++li) {
        const int dim = dims[li];
        const float* P0 = patch + lofs[li];
        const float s = 1.f / (float)(2 << li);
        float wy[4], wx[4];
        int ry[4], cx[4];
#pragma unroll
        for (int k = 0; k < 4; ++k) {
            float fy = (gy0 + k + 0.5f) * s - 0.5f;
            float fl = floorf(fy);
            wy[k] = fy - fl; ry[k] = (int)fl - baseY[li];
            float fx = (gx0 + k + 0.5f) * s - 0.5f;
            fl = floorf(fx);
            wx[k] = fx - fl; cx[k] = (int)fl - baseX[li];
        }
        const int r0 = ry[0], c0 = cx[0];
        const float* pp = P0 + r0 * dim + c0;
        float P[3][3];
#pragma unroll
        for (int r = 0; r < 3; ++r)
#pragma unroll
            for (int c = 0; c < 3; ++c) P[r][c] = pp[r * dim + c];
        float h[3][4];
#pragma unroll
        for (int j = 0; j < 4; ++j) {
            int dx = cx[j] - c0;
#pragma unroll
            for (int r = 0; r < 3; ++r) {
                float a = dx == 0 ? P[r][0] : P[r][1];
                float bb = dx == 0 ? P[r][1] : P[r][2];
                h[r][j] = a + wx[j] * (bb - a);
            }
        }
#pragma unroll
        for (int i = 0; i < 4; ++i) {
            int dy = ry[i] - r0;
#pragma unroll
            for (int j = 0; j < 4; ++j) {
                float h0 = dy == 0 ? h[0][j] : h[1][j];
                float h1 = dy == 0 ? h[1][j] : h[2][j];
                acc[i][j] += h0 + wy[i] * (h1 - h0);
            }
        }
    }

    const float bt = sBtot;
    float* op = out + ((size_t)b * 512 + gy0) * 512 + gx0;
#pragma unroll
    for (int i = 0; i < 4; ++i) {
        float4 v;
        v.x = (acc[i][0] + bt) * (1.f / 3.f);
        v.y = (acc[i][1] + bt) * (1.f / 3.f);
        v.z = (acc[i][2] + bt) * (1.f / 3.f);
        v.w = (acc[i][3] + bt) * (1.f / 3.f);
        *(float4*)(op + (size_t)i * 512) = v;
    }
}

extern "C" void kernel_launch(void* const* d_in, const int* in_sizes, int n_in,
                              void* d_out, int out_size, void* d_ws, size_t ws_size,
                              hipStream_t stream) {
    (void)in_sizes; (void)n_in; (void)out_size; (void)ws_size;
    const float* x = (const float*)d_in[0];
    float* ws = (float*)d_ws;
    float* out = (float*)d_out;

    // Workspace layout (float offsets):
    float* pyr1 = ws;                  // 256^2*24 = 1572864
    float* pyr3 = ws + 1572864;        //  64^2*24 =   98304
    float* dBase = ws + 1671168;       // d0..d6   = 2097024
    float* tmin0 = ws + 3768192;       // 6144
    float* tmax0 = ws + 3774336;       // 6144
    float* tmin1 = ws + 3780480;       // 1536
    float* tmax1 = ws + 3782016;       // 1536
    float* A = ws + 3783552;           // 168
    float* Bc = ws + 3783720;          // 168

    // Level 1 from raw x (initial _norm_pc is an affine no-op for the output)
    pyrdown_l1<<<NPLANES * 64, 256, 0, stream>>>(x, pyr1);
    pyrdown23<<<NPLANES * 16, 256, 0, stream>>>(pyr1, pyr3, dBase, tmin0, tmax0, tmin1, tmax1);
    fused_small_kernel<<<NPLANES, 1024, 0, stream>>>(pyr3, dBase, tmin0, tmax0, tmin1, tmax1, A, Bc);
    final_kernel<<<8 * 64, 256, 0, stream>>>(dBase, A, Bc, out);
}